// Round 3
// baseline (5644.153 us; speedup 1.0000x reference)
//
#include <hip/hip_runtime.h>
#include <hip/hip_bf16.h>
#include <cstddef>

// ---------------------------------------------------------------------------
// FusionAfterBEVSEDirect — bf16-storage / fp32-compute, 195 MiB workspace
// B=2 H=256 W=256  C=128 NH=8 DH=16 DI=256 DS=16 DC=4 KTOP=128 CR=64 CI=128
// P = 131072 tokens (token-major), N = 512 sequences of 256 tokens.
//
// ws (ushort elems):  R[0,16.7M) radS/rad3 | I[16.7M,33.5M) imgS->dcomb |
//                     U[33.5M,67.1M) x->xs->fuse_in | V[67.1M,100.7M) z
//                     + fp32 tail: WTfuse, MR, MRKV, IDX   (total ~195 MiB)
// d_out (50.3M ushort): qh+khvh -> t1 halves -> dt/btct/y/hmb halves -> final
// ---------------------------------------------------------------------------

#define PTOK   131072
#define WSEQ   256
#define HWPIX  65536

typedef unsigned short u16;
typedef unsigned int   u32;

__device__ __forceinline__ float b2f(u16 u) { return __uint_as_float((u32)u << 16); }
__device__ __forceinline__ u16   f2b(float f) {
    u32 x = __float_as_uint(f);
    return (u16)((x + 0x7fffu + ((x >> 16) & 1u)) >> 16);
}
__device__ __forceinline__ void unpack8(uint4 p, float* v) {
    const u32 a[4] = {p.x, p.y, p.z, p.w};
#pragma unroll
    for (int q = 0; q < 4; ++q) {
        v[2 * q]     = b2f((u16)(a[q] & 0xffffu));
        v[2 * q + 1] = b2f((u16)(a[q] >> 16));
    }
}

constexpr int AM_NCHW = 0, AM_TOK = 1, AM_LN = 2, AM_LNG = 3, AM_CAT = 4;
constexpr int EP_NONE = 0, EP_RELU = 1, EP_RES = 2, EP_SP = 3;

// ---------------- tiled GEMM: C(P,O) = epi(A(P,K) @ Bw(O,K)^T + bias), bf16 out
template<int AM, int EPI>
__global__ __launch_bounds__(256)
void gemm_k(const void* __restrict__ Apv, const void* __restrict__ Ap2v,
            const int* __restrict__ gidx, const float* __restrict__ stats,
            const float* __restrict__ lng, const float* __restrict__ lnb,
            int K, int Cin,
            const float* __restrict__ Bw, const float* __restrict__ bias,
            u16* __restrict__ Cout, int O, int Ostride)
{
    __shared__ float As[64][68];
    __shared__ float Bs[64][68];
    const int tid = threadIdx.x;
    const int t0 = blockIdx.x * 64;
    const int o0 = blockIdx.y * 64;
    const int tx = tid & 15, ty = tid >> 4;
    const int ti = tid >> 2, g = tid & 3;
    float acc[16];
#pragma unroll
    for (int i = 0; i < 16; ++i) acc[i] = 0.f;

    const int arow = t0 + ti;
    float mrow = 0.f, rrow = 1.f;
    int grow = arow;
    if (AM == AM_LN) { mrow = stats[2 * arow]; rrow = stats[2 * arow + 1]; }
    if (AM == AM_LNG) {
        const int n = arow >> 7;
        const int w = gidx[arow] & 255;
        grow = n * 256 + w;
        mrow = stats[2 * arow]; rrow = stats[2 * arow + 1];
    }

    for (int kc0 = 0; kc0 < K; kc0 += 64) {
        if (AM == AM_NCHW) {
            const float* Af = (const float*)Apv;
            const int cl = tid >> 6, wi = tid & 63;
            const int t = t0 + wi;
            const size_t base = (size_t)(t >> 16) * (size_t)Cin * HWPIX + (size_t)(t & (HWPIX - 1));
#pragma unroll
            for (int p = 0; p < 16; ++p) {
                const int c = kc0 + p * 4 + cl;
                As[p * 4 + cl][wi] = Af[base + (size_t)c * HWPIX];
            }
        } else {
            const u16* src; int rs, cb, row;
            if (AM == AM_CAT) {
                src = (kc0 & 128) ? (const u16*)Ap2v : (const u16*)Apv;
                rs = 128; cb = kc0 & 127; row = arow;
            } else if (AM == AM_LNG) {
                src = (const u16*)Apv; rs = 128; cb = kc0; row = grow;
            } else {
                src = (const u16*)Apv; rs = K; cb = kc0; row = arow;
            }
            const u16* rp = src + (size_t)row * rs + cb + g * 16;
            float v[16];
            uint4 pa = *(const uint4*)rp;
            uint4 pb = *(const uint4*)(rp + 8);
            unpack8(pa, v); unpack8(pb, v + 8);
            if (AM == AM_LN || AM == AM_LNG) {
                const int cbase = cb + g * 16;
#pragma unroll
                for (int p = 0; p < 16; ++p)
                    v[p] = (v[p] - mrow) * rrow * lng[cbase + p] + lnb[cbase + p];
            }
            const int c0 = g * 16;
#pragma unroll
            for (int p = 0; p < 16; ++p) As[c0 + p][ti] = v[p];
        }
        {
            const int oi = ti;
            const bool ok = (o0 + oi) < O;
            const float* rowp = Bw + (size_t)(o0 + oi) * K + kc0;
#pragma unroll
            for (int p = 0; p < 4; ++p) {
                const int cl = g * 4 + p * 16;
                float4 v = make_float4(0.f, 0.f, 0.f, 0.f);
                if (ok) v = *(const float4*)(rowp + cl);
                Bs[cl + 0][oi] = v.x; Bs[cl + 1][oi] = v.y;
                Bs[cl + 2][oi] = v.z; Bs[cl + 3][oi] = v.w;
            }
        }
        __syncthreads();
#pragma unroll 4
        for (int kc = 0; kc < 64; ++kc) {
            const float4 a = *(const float4*)&As[kc][tx * 4];
            const float4 b = *(const float4*)&Bs[kc][ty * 4];
            acc[0]  += a.x * b.x; acc[1]  += a.x * b.y; acc[2]  += a.x * b.z; acc[3]  += a.x * b.w;
            acc[4]  += a.y * b.x; acc[5]  += a.y * b.y; acc[6]  += a.y * b.z; acc[7]  += a.y * b.w;
            acc[8]  += a.z * b.x; acc[9]  += a.z * b.y; acc[10] += a.z * b.z; acc[11] += a.z * b.w;
            acc[12] += a.w * b.x; acc[13] += a.w * b.y; acc[14] += a.w * b.z; acc[15] += a.w * b.w;
        }
        __syncthreads();
    }
#pragma unroll
    for (int i = 0; i < 4; ++i) {
        const int t = t0 + tx * 4 + i;
#pragma unroll
        for (int j = 0; j < 4; ++j) {
            const int o = o0 + ty * 4 + j;
            if (o < O) {
                float v = acc[i * 4 + j];
                if (bias) v += bias[o];
                if (EPI == EP_RELU) v = fmaxf(v, 0.f);
                if (EPI == EP_SP)   v = fmaxf(v, 0.f) + log1pf(expf(-fabsf(v)));
                u16* dst = Cout + (size_t)t * Ostride + o;
                if (EPI == EP_RES)  v += b2f(*dst);
                *dst = f2b(v);
            }
        }
    }
}

// ---------------- per-token LN stats (mean, rstd) from bf16 rows of 128
__global__ __launch_bounds__(256)
void stats_kernel(const u16* __restrict__ X, float* __restrict__ MR, int ntok)
{
    const int r = blockIdx.x * 4 + (threadIdx.x >> 6);
    const int lane = threadIdx.x & 63;
    if (r >= ntok) return;
    const u16* row = X + (size_t)r * 128;
    const float x0 = b2f(row[lane]), x1 = b2f(row[lane + 64]);
    float s = x0 + x1;
#pragma unroll
    for (int off = 32; off; off >>= 1) s += __shfl_xor(s, off);
    const float m = s * (1.f / 128.f);
    const float e0 = x0 - m, e1 = x1 - m;
    float v = e0 * e0 + e1 * e1;
#pragma unroll
    for (int off = 32; off; off >>= 1) v += __shfl_xor(v, off);
    if (lane == 0) { MR[2 * r] = m; MR[2 * r + 1] = rsqrtf(v * (1.f / 128.f) + 1e-5f); }
}

// stats over gathered img rows (for kv LN)
__global__ __launch_bounds__(256)
void kv_stats_kernel(const u16* __restrict__ I, const int* __restrict__ idx,
                     float* __restrict__ MRKV)
{
    const int r = blockIdx.x * 4 + (threadIdx.x >> 6);   // 0..65535
    const int lane = threadIdx.x & 63;
    if (r >= 65536) return;
    const int n = r >> 7;
    const int w = idx[r] & 255;
    const u16* row = I + (size_t)(n * 256 + w) * 128;
    const float x0 = b2f(row[lane]), x1 = b2f(row[lane + 64]);
    float s = x0 + x1;
#pragma unroll
    for (int off = 32; off; off >>= 1) s += __shfl_xor(s, off);
    const float m = s * (1.f / 128.f);
    const float e0 = x0 - m, e1 = x1 - m;
    float v = e0 * e0 + e1 * e1;
#pragma unroll
    for (int off = 32; off; off >>= 1) v += __shfl_xor(v, off);
    if (lane == 0) { MRKV[2 * r] = m; MRKV[2 * r + 1] = rsqrtf(v * (1.f / 128.f) + 1e-5f); }
}

// ---------------- score MLP + deterministic top-128 (rank = lax.top_k position)
__global__ __launch_bounds__(256)
void score_select_kernel(const u16* __restrict__ radS, const u16* __restrict__ imgS,
                         const float* __restrict__ Ws1, const float* __restrict__ bs1,
                         const float* __restrict__ Ws2, const float* __restrict__ bs2,
                         int* __restrict__ idx)
{
    __shared__ float WT[256][64];   // Ws1^T; reused for scores after barrier
    const int tid = threadIdx.x, n = blockIdx.x;
    for (int i = tid; i < 16384; i += 256) { const int j = i >> 8, c = i & 255; WT[c][j] = Ws1[i]; }
    __syncthreads();
    float acc[64];
#pragma unroll
    for (int j = 0; j < 64; ++j) acc[j] = 0.f;
    const int t = n * WSEQ + tid;
    const u16* r0 = radS + (size_t)t * 128;
    const u16* r1 = imgS + (size_t)t * 128;
    for (int c = 0; c < 128; ++c) {
        const float v = b2f(r0[c]);
#pragma unroll
        for (int j = 0; j < 64; ++j) acc[j] += v * WT[c][j];
    }
    for (int c = 0; c < 128; ++c) {
        const float v = b2f(r1[c]);
#pragma unroll
        for (int j = 0; j < 64; ++j) acc[j] += v * WT[128 + c][j];
    }
    float s = bs2[0];
#pragma unroll
    for (int j = 0; j < 64; ++j) s += fmaxf(acc[j] + bs1[j], 0.f) * Ws2[j];
    __syncthreads();
    float* sc = &WT[0][0];
    sc[tid] = s;
    __syncthreads();
    int rank = 0;
    for (int j = 0; j < 256; ++j) {
        const float sj = sc[j];
        rank += (sj > s) || (sj == s && j < tid);
    }
    if (rank < 128) idx[n * 128 + rank] = tid;
}

// ---------------- attention: block = (n, head); in-place ao over qh (bf16)
__global__ __launch_bounds__(256)
void attn_kernel(u16* __restrict__ qh, const u16* __restrict__ khvh)
{
    __shared__ float Ks[128 * 16];
    __shared__ float Vs[128 * 16];
    const int n = blockIdx.x >> 3, hd = blockIdx.x & 7;
    const int tid = threadIdx.x;
    {
        const int d = tid & 15, ktb = tid >> 4;
#pragma unroll
        for (int p = 0; p < 8; ++p) {
            const int kt = ktb + p * 16;
            const u16* src = khvh + (size_t)(n * 128 + kt) * 256 + hd * 16 + d;
            Ks[kt * 16 + d] = b2f(src[0]);
            Vs[kt * 16 + d] = b2f(src[128]);
        }
    }
    __syncthreads();
    const int t = n * WSEQ + tid;
    u16* qp = qh + (size_t)t * 128 + hd * 16;
    float q[16];
#pragma unroll
    for (int d = 0; d < 16; ++d) q[d] = b2f(qp[d]);
    float m = -1e30f, l = 0.f;
    float acc[16];
#pragma unroll
    for (int d = 0; d < 16; ++d) acc[d] = 0.f;
    for (int kt = 0; kt < 128; ++kt) {
        const float* kr = &Ks[kt * 16];
        float s = 0.f;
#pragma unroll
        for (int d = 0; d < 16; ++d) s += q[d] * kr[d];
        s *= 0.25f;
        const float mn = fmaxf(m, s);
        const float corr = __expf(m - mn);
        const float p = __expf(s - mn);
        l = l * corr + p;
        const float* vr = &Vs[kt * 16];
#pragma unroll
        for (int d = 0; d < 16; ++d) acc[d] = acc[d] * corr + p * vr[d];
        m = mn;
    }
    const float inv = 1.f / l;
#pragma unroll
    for (int d = 0; d < 16; ++d) qp[d] = f2b(acc[d] * inv);
}

// ---------------- depthwise causal conv (DC=4) + silu, IN PLACE over x (bf16)
// one thread per (n, di), full 256-step line; window held in registers.
__global__ __launch_bounds__(256)
void dwconv_kernel(u16* __restrict__ x, const float* __restrict__ kw,
                   const float* __restrict__ bdw)
{
    const int di = threadIdx.x;
    const int n = blockIdx.x;
    const float k0 = kw[di * 4 + 0], k1 = kw[di * 4 + 1];
    const float k2 = kw[di * 4 + 2], k3 = kw[di * 4 + 3];
    const float bb = bdw[di];
    float x3 = 0.f, x2 = 0.f, x1 = 0.f;
    for (int w = 0; w < 256; ++w) {
        const size_t o = (size_t)(n * WSEQ + w) * 256 + di;
        const float x0 = b2f(x[o]);
        const float v = x3 * k0 + x2 * k1 + x1 * k2 + x0 * k3 + bb;
        x[o] = f2b(v * (1.f / (1.f + __expf(-v))));
        x3 = x2; x2 = x1; x1 = x0;
    }
}

// ---------------- bidirectional selective scan (one token-half per call)
__global__ __launch_bounds__(256)
void scan_kernel(const u16* __restrict__ xs, const u16* __restrict__ dt,
                 const u16* __restrict__ btct, const float* __restrict__ A_log,
                 const float* __restrict__ Dp, const u16* __restrict__ z,
                 u16* __restrict__ yf)
{
    __shared__ float Bs[256][16];
    __shared__ float Cs[256][16];
    const int di = threadIdx.x, n = blockIdx.x;   // n relative to half
    for (int i = di; i < 256 * 32; i += 256) {
        const int w = i >> 5, c = i & 31;
        const float v = b2f(btct[(size_t)(n * WSEQ + w) * 32 + c]);
        if (c < 16) Bs[w][c] = v; else Cs[w][c - 16] = v;
    }
    __syncthreads();
    float a[16];
#pragma unroll
    for (int s = 0; s < 16; ++s) a[s] = -__expf(A_log[di * 16 + s]);
    const float dpv = Dp[di];
    float h[16];
#pragma unroll
    for (int s = 0; s < 16; ++s) h[s] = 0.f;
    for (int w = 0; w < 256; ++w) {
        const size_t t = (size_t)(n * WSEQ + w);
        const float dtv = b2f(dt[t * 256 + di]);
        const float xv = b2f(xs[t * 256 + di]);
        const float dx = dtv * xv;
        float yv = 0.f;
#pragma unroll
        for (int s = 0; s < 16; ++s) {
            const float e = __expf(dtv * a[s]);
            h[s] = e * h[s] + dx * Bs[w][s];
            yv += h[s] * Cs[w][s];
        }
        yf[t * 256 + di] = f2b(yv);
    }
#pragma unroll
    for (int s = 0; s < 16; ++s) h[s] = 0.f;
    for (int w = 255; w >= 0; --w) {
        const size_t t = (size_t)(n * WSEQ + w);
        const float dtv = b2f(dt[t * 256 + di]);
        const float xv = b2f(xs[t * 256 + di]);
        const float dx = dtv * xv;
        float yv = 0.f;
#pragma unroll
        for (int s = 0; s < 16; ++s) {
            const float e = __expf(dtv * a[s]);
            h[s] = e * h[s] + dx * Bs[w][s];
            yv += h[s] * Cs[w][s];
        }
        const float zv = b2f(z[t * 256 + di]);
        const float silz = zv * (1.f / (1.f + __expf(-zv)));
        const float tot = b2f(yf[t * 256 + di]) + yv + dpv * xv;
        yf[t * 256 + di] = f2b(tot * silz);
    }
}

// ---------------- hmb <- gamma*rad3 + gammah*hmb (bf16, in place)
__global__ __launch_bounds__(256)
void precomb_kernel(const u16* __restrict__ rad3, u16* __restrict__ hmb,
                    const float* __restrict__ gamma, const float* __restrict__ gammah)
{
    const size_t i = (size_t)blockIdx.x * 256 + threadIdx.x;
    hmb[i] = f2b(gamma[0] * b2f(rad3[i]) + gammah[0] * b2f(hmb[i]));
}

// ---------------- gate + radar_enh + assemble fuse_in (bf16, P x 192)
__global__ __launch_bounds__(256)
void gate_kernel(const float* __restrict__ radar, const float* __restrict__ image,
                 const float* __restrict__ Wg, const float* __restrict__ bg,
                 const u16* __restrict__ dcomb, u16* __restrict__ fin)
{
    __shared__ float WT[192][64];
    const int tid = threadIdx.x;
    const int bh = blockIdx.x;
    const int b = bh >> 8, h = bh & 255;
    for (int i = tid; i < 64 * 192; i += 256) { const int o = i / 192, c = i % 192; WT[c][o] = Wg[i]; }
    __syncthreads();
    float acc[64];
#pragma unroll
    for (int o = 0; o < 64; ++o) acc[o] = 0.f;
    const size_t rbase = (size_t)b * 64 * HWPIX + (size_t)h * 256 + tid;
    const size_t ibase = (size_t)b * 128 * HWPIX + (size_t)h * 256 + tid;
    for (int c = 0; c < 64; ++c) {
        const float v = radar[rbase + (size_t)c * HWPIX];
#pragma unroll
        for (int o = 0; o < 64; ++o) acc[o] += v * WT[c][o];
    }
    for (int c = 0; c < 128; ++c) {
        const float v = image[ibase + (size_t)c * HWPIX];
#pragma unroll
        for (int o = 0; o < 64; ++o) acc[o] += v * WT[64 + c][o];
    }
    const float wm = fmaxf(1.f - 0.7f * (float)h * (1.f / 255.f), 0.3f);
    const size_t t = (size_t)bh * 256 + tid;
    u16* fo = fin + t * 192;
    for (int o = 0; o < 64; ++o) {
        const float gate = wm / (1.f + __expf(-(acc[o] + bg[o])));
        fo[o] = f2b(radar[rbase + (size_t)o * HWPIX] + gate * b2f(dcomb[t * 64 + o]));
    }
    for (int c = 0; c < 128; ++c)
        fo[64 + c] = f2b(image[ibase + (size_t)c * HWPIX]);
}

// ---------------- Wfuse (o,c,kh,kw) -> Wt[(kh*3+kw)][c][o]  (fp32)
__global__ __launch_bounds__(256)
void wprep_kernel(const float* __restrict__ Wfuse, float* __restrict__ Wt)
{
    const int i = blockIdx.x * 256 + threadIdx.x;
    if (i >= 192 * 192 * 9) return;
    const int o = i / 1728, r = i % 1728;
    const int c = r / 9, kk = r % 9;
    Wt[((size_t)(kk * 192 + c)) * 192 + o] = Wfuse[i];
}

// ---------------- 3x3 SAME conv over fuse_in (bf16) + BN + relu -> NCHW fp32
__global__ __launch_bounds__(192)
void conv3x3_kernel(const u16* __restrict__ fin, const float* __restrict__ Wt,
                    const float* __restrict__ bn_g, const float* __restrict__ bn_b,
                    const float* __restrict__ bn_m, const float* __restrict__ bn_v,
                    float* __restrict__ out)
{
    const int tid = threadIdx.x;
    const int tg = tid / 24, og = tid % 24;
    const int t0 = blockIdx.x * 32;
    const int b = t0 >> 16, rem = t0 & (HWPIX - 1), h = rem >> 8, w0 = rem & 255;
    const int wbase = w0 + tg * 4;
    const int o0 = og * 8;
    float acc[32];
#pragma unroll
    for (int i = 0; i < 32; ++i) acc[i] = 0.f;

    for (int kh = 0; kh < 3; ++kh) {
        const int hh = h + kh - 1;
        if (hh < 0 || hh >= 256) continue;
        const u16* finrow = fin + (size_t)(b * 256 + hh) * 256 * 192;
        for (int kw = 0; kw < 3; ++kw) {
            const float* wp = Wt + (size_t)(kh * 3 + kw) * 192 * 192 + o0;
            const u16* ap[4];
            float am[4];
#pragma unroll
            for (int i = 0; i < 4; ++i) {
                const int ww = wbase + i + kw - 1;
                am[i] = (ww >= 0 && ww < 256) ? 1.f : 0.f;
                const int wc = min(max(ww, 0), 255);
                ap[i] = finrow + (size_t)wc * 192;
            }
#pragma unroll 2
            for (int c = 0; c < 192; ++c) {
                const float4 b0 = *(const float4*)(wp + (size_t)c * 192);
                const float4 b1 = *(const float4*)(wp + (size_t)c * 192 + 4);
#pragma unroll
                for (int i = 0; i < 4; ++i) {
                    const float av = am[i] * b2f(ap[i][c]);
                    acc[i * 8 + 0] += av * b0.x; acc[i * 8 + 1] += av * b0.y;
                    acc[i * 8 + 2] += av * b0.z; acc[i * 8 + 3] += av * b0.w;
                    acc[i * 8 + 4] += av * b1.x; acc[i * 8 + 5] += av * b1.y;
                    acc[i * 8 + 6] += av * b1.z; acc[i * 8 + 7] += av * b1.w;
                }
            }
        }
    }
#pragma unroll
    for (int j = 0; j < 8; ++j) {
        const int o = o0 + j;
        const float sc = bn_g[o] * rsqrtf(bn_v[o] + 1e-5f);
        const float sh = bn_b[o] - bn_m[o] * sc;
#pragma unroll
        for (int i = 0; i < 4; ++i) {
            const float v = fmaxf(acc[i * 8 + j] * sc + sh, 0.f);
            out[(size_t)(b * 192 + o) * HWPIX + (size_t)h * 256 + wbase + i] = v;
        }
    }
}

// ---------------------------------------------------------------------------
extern "C" void kernel_launch(void* const* d_in, const int* in_sizes, int n_in,
                              void* d_out, int out_size, void* d_ws, size_t ws_size,
                              hipStream_t stream)
{
    const float* image  = (const float*)d_in[0];
    const float* radar  = (const float*)d_in[1];
    const float* W_img  = (const float*)d_in[2];
    const float* W_rad  = (const float*)d_in[3];
    const float* g_q    = (const float*)d_in[4];
    const float* b_q    = (const float*)d_in[5];
    const float* g_kv   = (const float*)d_in[6];
    const float* b_kv   = (const float*)d_in[7];
    const float* g2     = (const float*)d_in[8];
    const float* b2     = (const float*)d_in[9];
    const float* Ws1    = (const float*)d_in[10];
    const float* bs1    = (const float*)d_in[11];
    const float* Ws2    = (const float*)d_in[12];
    const float* bs2    = (const float*)d_in[13];
    const float* Wqkv   = (const float*)d_in[14];
    const float* bqkv   = (const float*)d_in[15];
    const float* Wo     = (const float*)d_in[16];
    const float* bo     = (const float*)d_in[17];
    const float* Wf1    = (const float*)d_in[18];
    const float* bf1    = (const float*)d_in[19];
    const float* Wf2    = (const float*)d_in[20];
    const float* bf2    = (const float*)d_in[21];
    const float* W_delta= (const float*)d_in[22];
    const float* gamma  = (const float*)d_in[23];
    const float* gammah = (const float*)d_in[24];
    const float* Wg     = (const float*)d_in[25];
    const float* bg     = (const float*)d_in[26];
    const float* Wfuse  = (const float*)d_in[27];
    const float* bn_g   = (const float*)d_in[28];
    const float* bn_b   = (const float*)d_in[29];
    const float* bn_m   = (const float*)d_in[30];
    const float* bn_v   = (const float*)d_in[31];
    const float* W_hin  = (const float*)d_in[32];
    const float* conv_dw= (const float*)d_in[33];
    const float* b_dw   = (const float*)d_in[34];
    const float* W_dt   = (const float*)d_in[35];
    const float* b_dt   = (const float*)d_in[36];
    const float* W_Bp   = (const float*)d_in[37];
    const float* W_Cp   = (const float*)d_in[38];
    const float* A_log  = (const float*)d_in[39];
    const float* Dp     = (const float*)d_in[40];
    const float* W_hout = (const float*)d_in[41];
    float* out = (float*)d_out;

    // ---- workspace (ushort elems) ----
    u16* wsu = (u16*)d_ws;
    u16* R = wsu;                      // radS -> rad2 -> rad3
    u16* I = wsu + 16777216u;          // imgS; later dcomb
    u16* U = wsu + 33554432u;          // x -> xs -> fuse_in
    u16* V = wsu + 67108864u;          // z
    float* ftail = (float*)(wsu + 100663296u);
    float* WTf   = ftail;              // 331,776
    float* MR    = ftail + 331776u;    // 262,144 (P mean/rstd pairs)
    float* MRKV  = ftail + 593920u;    // 131,072
    int*   IDX   = (int*)(ftail + 724992u);  // 65,536
    // ws total = 204,488,704 bytes (~195 MiB)

    // ---- d_out as ushort scratch (50,331,648 elems) ----
    u16* ob  = (u16*)d_out;
    u16* QH  = ob;                     // P*128
    u16* KVH = ob + 16777216u;         // 65536*256
    u16* T1  = ob;                     // per-half FFN hidden 65536*512
    u16* DT  = ob;                     // per-half 65536*256
    u16* BC  = ob + 16777216u;         // per-half 65536*32
    u16* Y   = ob + 18874368u;         // per-half 65536*256
    u16* HMB = ob + 35651584u;         // per-half 65536*128
    u16* DC  = I;                      // dcomb P*64 (imgS dead)

    wprep_kernel<<<1296, 256, 0, stream>>>(Wfuse, WTf);

    // conv1x1 to token-major bf16
    gemm_k<AM_NCHW, EP_NONE><<<dim3(2048, 2), 256, 0, stream>>>(image, nullptr, nullptr, nullptr, nullptr, nullptr, 128, 128, W_img, nullptr, I, 128, 128);
    gemm_k<AM_NCHW, EP_NONE><<<dim3(2048, 2), 256, 0, stream>>>(radar, nullptr, nullptr, nullptr, nullptr, nullptr,  64,  64, W_rad, nullptr, R, 128, 128);

    // scoring + top-128
    score_select_kernel<<<512, 256, 0, stream>>>(R, I, Ws1, bs1, Ws2, bs2, IDX);

    // LN stats (q from R; kv from gathered I)
    stats_kernel<<<32768, 256, 0, stream>>>(R, MR, PTOK);
    kv_stats_kernel<<<16384, 256, 0, stream>>>(I, IDX, MRKV);

    // qh = LN(R)@Wq^T + bq ; khvh = LN(gather(I))@[Wk;Wv]^T + [bk;bv]
    gemm_k<AM_LN,  EP_NONE><<<dim3(2048, 2), 256, 0, stream>>>(R, nullptr, nullptr, MR, g_q, b_q, 128, 0, Wqkv, bqkv, QH, 128, 128);
    gemm_k<AM_LNG, EP_NONE><<<dim3(1024, 4), 256, 0, stream>>>(I, nullptr, IDX, MRKV, g_kv, b_kv, 128, 0, Wqkv + 16384, bqkv + 128, KVH, 256, 256);

    // attention in place; rad2 = R + ao@Wo^T + bo
    attn_kernel<<<4096, 256, 0, stream>>>(QH, KVH);
    gemm_k<AM_TOK, EP_RES><<<dim3(2048, 2), 256, 0, stream>>>(QH, nullptr, nullptr, nullptr, nullptr, nullptr, 128, 0, Wo, bo, R, 128, 128);

    // FFN (LN folded), hidden chunked through d_out in 2 halves
    stats_kernel<<<32768, 256, 0, stream>>>(R, MR, PTOK);
    for (int hfl = 0; hfl < 2; ++hfl) {
        const size_t off = (size_t)hfl * 65536u;
        gemm_k<AM_LN,  EP_RELU><<<dim3(1024, 8), 256, 0, stream>>>(R + off * 128, nullptr, nullptr, MR + off * 2, g2, b2, 128, 0, Wf1, bf1, T1, 512, 512);
        gemm_k<AM_TOK, EP_RES ><<<dim3(1024, 2), 256, 0, stream>>>(T1, nullptr, nullptr, nullptr, nullptr, nullptr, 512, 0, Wf2, bf2, R + off * 128, 128, 128);
    }

    // xz: x -> U, z -> V  (A = [rad3 ; imgS], K=256)
    gemm_k<AM_CAT, EP_NONE><<<dim3(2048, 4), 256, 0, stream>>>(R, I, nullptr, nullptr, nullptr, nullptr, 256, 0, W_hin, nullptr, U, 256, 256);
    gemm_k<AM_CAT, EP_NONE><<<dim3(2048, 4), 256, 0, stream>>>(R, I, nullptr, nullptr, nullptr, nullptr, 256, 0, W_hin + 65536, nullptr, V, 256, 256);

    // depthwise causal conv + silu, in place: U: x -> xs
    dwconv_kernel<<<512, 256, 0, stream>>>(U, conv_dw, b_dw);

    // SSM in 2 token-halves through d_out
    for (int hfl = 0; hfl < 2; ++hfl) {
        const size_t off = (size_t)hfl * 65536u;
        u16* xs = U + off * 256;
        u16* z  = V + off * 256;
        gemm_k<AM_TOK, EP_SP  ><<<dim3(1024, 4), 256, 0, stream>>>(xs, nullptr, nullptr, nullptr, nullptr, nullptr, 256, 0, W_dt, b_dt, DT, 256, 256);
        gemm_k<AM_TOK, EP_NONE><<<dim3(1024, 1), 256, 0, stream>>>(xs, nullptr, nullptr, nullptr, nullptr, nullptr, 256, 0, W_Bp, nullptr, BC, 16, 32);
        gemm_k<AM_TOK, EP_NONE><<<dim3(1024, 1), 256, 0, stream>>>(xs, nullptr, nullptr, nullptr, nullptr, nullptr, 256, 0, W_Cp, nullptr, BC + 16, 16, 32);
        scan_kernel<<<256, 256, 0, stream>>>(xs, DT, BC, A_log, Dp, z, Y);
        gemm_k<AM_TOK, EP_NONE><<<dim3(1024, 2), 256, 0, stream>>>(Y, nullptr, nullptr, nullptr, nullptr, nullptr, 256, 0, W_hout, nullptr, HMB, 128, 128);
        precomb_kernel<<<32768, 256, 0, stream>>>(R + off * 128, HMB, gamma, gammah);
        gemm_k<AM_TOK, EP_NONE><<<dim3(1024, 1), 256, 0, stream>>>(HMB, nullptr, nullptr, nullptr, nullptr, nullptr, 128, 0, W_delta, nullptr, DC + off * 64, 64, 64);
    }

    // gate + radar_enh + fuse_in (U, xs dead)
    gate_kernel<<<512, 256, 0, stream>>>(radar, image, Wg, bg, DC, U);

    // final 3x3 conv + BN + relu -> d_out (fp32), rewrites all scratch
    conv3x3_kernel<<<4096, 192, 0, stream>>>(U, WTf, bn_g, bn_b, bn_m, bn_v, out);
}

// Round 4
// 2262.242 us; speedup vs baseline: 2.4949x; 2.4949x over previous
//
#include <hip/hip_runtime.h>
#include <hip/hip_bf16.h>
#include <cstddef>

// ---------------------------------------------------------------------------
// FusionAfterBEVSEDirect — bf16 storage, MFMA compute (round 4)
// B=2 H=256 W=256  C=128 NH=8 DH=16 DI=256 DS=16 DC=4 KTOP=128 CR=64 CI=128
// P = 131072 tokens (token-major), N = 512 sequences of 256 tokens.
// All GEMM-shaped work on v_mfma_f32_16x16x32_bf16 (128x128 tile, 4 waves,
// each 64x64 = 4x4 MFMA tiles). conv3x3 = implicit GEMM, K=1728.
// ws ~195 MiB (same slabs as round 3); d_out doubles as staged scratch.
// ---------------------------------------------------------------------------

#define PTOK   131072
#define WSEQ   256
#define HWPIX  65536

typedef unsigned short u16;
typedef unsigned int   u32;
typedef __bf16 bf16x8 __attribute__((ext_vector_type(8)));
typedef float  f32x4  __attribute__((ext_vector_type(4)));

__device__ __forceinline__ float b2f(u16 u) { return __uint_as_float((u32)u << 16); }
__device__ __forceinline__ u16   f2b(float f) {
    u32 x = __float_as_uint(f);
    return (u16)((x + 0x7fffu + ((x >> 16) & 1u)) >> 16);
}
__device__ __forceinline__ u32 pk2(float a, float b) {
    return (u32)f2b(a) | ((u32)f2b(b) << 16);
}
__device__ __forceinline__ void unpack8(uint4 p, float* v) {
    const u32 a[4] = {p.x, p.y, p.z, p.w};
#pragma unroll
    for (int q = 0; q < 4; ++q) {
        v[2 * q]     = b2f((u16)(a[q] & 0xffffu));
        v[2 * q + 1] = b2f((u16)(a[q] >> 16));
    }
}

constexpr int AM_NCHW = 0, AM_TOK = 1, AM_LN = 2, AM_LNG = 3, AM_CAT = 4;
constexpr int EP_NONE = 0, EP_RELU = 1, EP_RES = 2, EP_SP = 3;

// ---------------- MFMA GEMM: C(M,O) = epi(A(M,K) @ Bw(O,K)^T + bias)
// tile 128x128, block=256 (4 waves in 2x2), K-step 64. A bf16 (or NCHW fp32
// with on-the-fly convert), Bw fp32 -> bf16 on staging. Output bf16.
template<int AM, int EPI>
__global__ __launch_bounds__(256)
void mgemm(const void* __restrict__ Apv, const void* __restrict__ Ap2v,
           const int* __restrict__ gidx, const float* __restrict__ stats,
           const float* __restrict__ lng, const float* __restrict__ lnb,
           int K, int Cin,
           const float* __restrict__ Bw, const float* __restrict__ bias,
           u16* __restrict__ Cout, int O, int Ostride)
{
    __shared__ u16 Als[128 * 72];
    __shared__ u16 Bls[128 * 72];
    const int tid = threadIdx.x;
    const int t0 = blockIdx.x * 128;
    const int o0 = blockIdx.y * 128;
    const int lane = tid & 63, wv = tid >> 6;
    const int wm = (wv & 1) * 64, wn = (wv >> 1) * 64;
    const int fc = lane & 15, quad = lane >> 4;

    f32x4 acc[4][4];
#pragma unroll
    for (int i = 0; i < 4; ++i)
#pragma unroll
        for (int j = 0; j < 4; ++j) acc[i][j] = {0.f, 0.f, 0.f, 0.f};

    // staging thread mapping
    const int srow = tid >> 1;             // 0..127
    const int sseg = (tid & 1) * 32;       // k sub-offset

    // per-row precompute for LN modes
    float mrow = 0.f, rrow = 1.f;
    int grow = t0 + srow;
    if (AM == AM_LN) { mrow = stats[2 * (t0 + srow)]; rrow = stats[2 * (t0 + srow) + 1]; }
    if (AM == AM_LNG) {
        const int ar = t0 + srow;
        grow = (ar >> 7) * 256 + (gidx[ar] & 255);
        mrow = stats[2 * ar]; rrow = stats[2 * ar + 1];
    }

    for (int kc0 = 0; kc0 < K; kc0 += 64) {
        // ---- stage A ----
        if (AM == AM_NCHW) {
            const float* Af = (const float*)Apv;
            const int tl = tid & 127, cg = (tid >> 7) * 32;
            const int t = t0 + tl;
            const size_t base = (size_t)(t >> 16) * (size_t)Cin * HWPIX + (size_t)(t & (HWPIX - 1));
#pragma unroll 8
            for (int p = 0; p < 32; ++p) {
                const int c = kc0 + cg + p;
                Als[tl * 72 + cg + p] = f2b(Af[base + (size_t)c * HWPIX]);
            }
        } else {
            const u16* src; int rs, cb, row;
            if (AM == AM_CAT) {
                src = (kc0 & 128) ? (const u16*)Ap2v : (const u16*)Apv;
                rs = 128; cb = (kc0 & 127) + sseg; row = t0 + srow;
            } else if (AM == AM_LNG) {
                src = (const u16*)Apv; rs = 128; cb = kc0 + sseg; row = grow;
            } else {
                src = (const u16*)Apv; rs = K; cb = kc0 + sseg; row = t0 + srow;
            }
            const u16* rp = src + (size_t)row * rs + cb;
            uint4 pa = *(const uint4*)rp;
            uint4 pb = *(const uint4*)(rp + 8);
            uint4 pc = *(const uint4*)(rp + 16);
            uint4 pd = *(const uint4*)(rp + 24);
            if (AM == AM_LN || AM == AM_LNG) {
                float v[32];
                unpack8(pa, v); unpack8(pb, v + 8); unpack8(pc, v + 16); unpack8(pd, v + 24);
                const int c0 = cb;   // global column base (K==128 for LN modes)
#pragma unroll
                for (int p = 0; p < 32; ++p)
                    v[p] = (v[p] - mrow) * rrow * lng[c0 + p] + lnb[c0 + p];
                uint4 q0, q1, q2, q3;
                q0.x = pk2(v[0], v[1]);   q0.y = pk2(v[2], v[3]);   q0.z = pk2(v[4], v[5]);   q0.w = pk2(v[6], v[7]);
                q1.x = pk2(v[8], v[9]);   q1.y = pk2(v[10], v[11]); q1.z = pk2(v[12], v[13]); q1.w = pk2(v[14], v[15]);
                q2.x = pk2(v[16], v[17]); q2.y = pk2(v[18], v[19]); q2.z = pk2(v[20], v[21]); q2.w = pk2(v[22], v[23]);
                q3.x = pk2(v[24], v[25]); q3.y = pk2(v[26], v[27]); q3.z = pk2(v[28], v[29]); q3.w = pk2(v[30], v[31]);
                pa = q0; pb = q1; pc = q2; pd = q3;
            }
            uint4* dst = (uint4*)&Als[srow * 72 + sseg];
            dst[0] = pa; dst[1] = pb; dst[2] = pc; dst[3] = pd;
        }
        // ---- stage B (fp32 weights -> bf16) ----
        {
            const int orow = srow;
            const bool ok = (o0 + orow) < O;
            uint4 q0 = {0,0,0,0}, q1 = {0,0,0,0}, q2 = {0,0,0,0}, q3 = {0,0,0,0};
            if (ok) {
                const float* rp = Bw + (size_t)(o0 + orow) * K + kc0 + sseg;
                float v[32];
#pragma unroll
                for (int p = 0; p < 8; ++p) {
                    const float4 f = *(const float4*)(rp + p * 4);
                    v[p * 4 + 0] = f.x; v[p * 4 + 1] = f.y; v[p * 4 + 2] = f.z; v[p * 4 + 3] = f.w;
                }
                q0.x = pk2(v[0], v[1]);   q0.y = pk2(v[2], v[3]);   q0.z = pk2(v[4], v[5]);   q0.w = pk2(v[6], v[7]);
                q1.x = pk2(v[8], v[9]);   q1.y = pk2(v[10], v[11]); q1.z = pk2(v[12], v[13]); q1.w = pk2(v[14], v[15]);
                q2.x = pk2(v[16], v[17]); q2.y = pk2(v[18], v[19]); q2.z = pk2(v[20], v[21]); q2.w = pk2(v[22], v[23]);
                q3.x = pk2(v[24], v[25]); q3.y = pk2(v[26], v[27]); q3.z = pk2(v[28], v[29]); q3.w = pk2(v[30], v[31]);
            }
            uint4* dst = (uint4*)&Bls[orow * 72 + sseg];
            dst[0] = q0; dst[1] = q1; dst[2] = q2; dst[3] = q3;
        }
        __syncthreads();
        // ---- MFMA over the 64-K tile, two 32-K chunks ----
#pragma unroll
        for (int kc = 0; kc < 64; kc += 32) {
            bf16x8 aF[4], bF[4];
#pragma unroll
            for (int mt = 0; mt < 4; ++mt)
                aF[mt] = *(const bf16x8*)&Als[(wm + mt * 16 + fc) * 72 + kc + quad * 8];
#pragma unroll
            for (int nt = 0; nt < 4; ++nt)
                bF[nt] = *(const bf16x8*)&Bls[(wn + nt * 16 + fc) * 72 + kc + quad * 8];
#pragma unroll
            for (int mt = 0; mt < 4; ++mt)
#pragma unroll
                for (int nt = 0; nt < 4; ++nt)
                    acc[mt][nt] = __builtin_amdgcn_mfma_f32_16x16x32_bf16(aF[mt], bF[nt], acc[mt][nt], 0, 0, 0);
        }
        __syncthreads();
    }

    // ---- epilogue ----
#pragma unroll
    for (int nt = 0; nt < 4; ++nt) {
        const int o = o0 + wn + nt * 16 + fc;
        if (o >= O) continue;
        const float bv = bias ? bias[o] : 0.f;
#pragma unroll
        for (int mt = 0; mt < 4; ++mt) {
#pragma unroll
            for (int reg = 0; reg < 4; ++reg) {
                const int t = t0 + wm + mt * 16 + quad * 4 + reg;
                float v = acc[mt][nt][reg] + bv;
                if (EPI == EP_RELU) v = fmaxf(v, 0.f);
                if (EPI == EP_SP)   v = fmaxf(v, 0.f) + log1pf(expf(-fabsf(v)));
                u16* dst = Cout + (size_t)t * Ostride + o;
                if (EPI == EP_RES)  v += b2f(*dst);
                *dst = f2b(v);
            }
        }
    }
}

// ---------------- conv3x3 as implicit MFMA GEMM; K = 9*192 = 1728
// A rows = fuse_in tokens remapped by (kh,kw) with border masking;
// B = Wc[kk][o][c] bf16 (pre-transposed). Epilogue: BN + relu -> NCHW fp32.
__global__ __launch_bounds__(256)
void conv3x3_mfma(const u16* __restrict__ fin, const u16* __restrict__ Wc,
                  const float* __restrict__ bn_g, const float* __restrict__ bn_b,
                  const float* __restrict__ bn_m, const float* __restrict__ bn_v,
                  float* __restrict__ out)
{
    __shared__ u16 Als[128 * 72];
    __shared__ u16 Bls[128 * 72];
    const int tid = threadIdx.x;
    const int t0 = blockIdx.x * 128;
    const int o0 = blockIdx.y * 128;
    const int lane = tid & 63, wv = tid >> 6;
    const int wm = (wv & 1) * 64, wn = (wv >> 1) * 64;
    const int fc = lane & 15, quad = lane >> 4;

    f32x4 acc[4][4];
#pragma unroll
    for (int i = 0; i < 4; ++i)
#pragma unroll
        for (int j = 0; j < 4; ++j) acc[i][j] = {0.f, 0.f, 0.f, 0.f};

    const int srow = tid >> 1;
    const int sseg = (tid & 1) * 32;
    const int t = t0 + srow;
    const int h = (t >> 8) & 255, w = t & 255;

    for (int chunk = 0; chunk < 27; ++chunk) {
        const int kk = chunk / 3;            // 0..8
        const int c0 = (chunk % 3) * 64;     // 0,64,128
        const int kh = kk / 3, kw = kk % 3;
        // ---- stage A ----
        {
            const int hh = h + kh - 1, ww = w + kw - 1;
            const bool ok = ((unsigned)hh < 256u) && ((unsigned)ww < 256u);
            uint4 p0 = {0,0,0,0}, p1 = {0,0,0,0}, p2 = {0,0,0,0}, p3 = {0,0,0,0};
            if (ok) {
                const u16* rp = fin + (size_t)(t + (kh - 1) * 256 + (kw - 1)) * 192 + c0 + sseg;
                p0 = *(const uint4*)rp; p1 = *(const uint4*)(rp + 8);
                p2 = *(const uint4*)(rp + 16); p3 = *(const uint4*)(rp + 24);
            }
            uint4* dst = (uint4*)&Als[srow * 72 + sseg];
            dst[0] = p0; dst[1] = p1; dst[2] = p2; dst[3] = p3;
        }
        // ---- stage B ----
        {
            const int orow = srow;
            const bool ok = (o0 + orow) < 192;
            uint4 p0 = {0,0,0,0}, p1 = {0,0,0,0}, p2 = {0,0,0,0}, p3 = {0,0,0,0};
            if (ok) {
                const u16* rp = Wc + (size_t)kk * 36864 + (size_t)(o0 + orow) * 192 + c0 + sseg;
                p0 = *(const uint4*)rp; p1 = *(const uint4*)(rp + 8);
                p2 = *(const uint4*)(rp + 16); p3 = *(const uint4*)(rp + 24);
            }
            uint4* dst = (uint4*)&Bls[orow * 72 + sseg];
            dst[0] = p0; dst[1] = p1; dst[2] = p2; dst[3] = p3;
        }
        __syncthreads();
#pragma unroll
        for (int kc = 0; kc < 64; kc += 32) {
            bf16x8 aF[4], bF[4];
#pragma unroll
            for (int mt = 0; mt < 4; ++mt)
                aF[mt] = *(const bf16x8*)&Als[(wm + mt * 16 + fc) * 72 + kc + quad * 8];
#pragma unroll
            for (int nt = 0; nt < 4; ++nt)
                bF[nt] = *(const bf16x8*)&Bls[(wn + nt * 16 + fc) * 72 + kc + quad * 8];
#pragma unroll
            for (int mt = 0; mt < 4; ++mt)
#pragma unroll
                for (int nt = 0; nt < 4; ++nt)
                    acc[mt][nt] = __builtin_amdgcn_mfma_f32_16x16x32_bf16(aF[mt], bF[nt], acc[mt][nt], 0, 0, 0);
        }
        __syncthreads();
    }

    // ---- epilogue: BN + relu -> NCHW fp32 ----
    const int bb = t0 >> 16, hb = (t0 >> 8) & 255, w0 = t0 & 255;
#pragma unroll
    for (int nt = 0; nt < 4; ++nt) {
        const int o = o0 + wn + nt * 16 + fc;
        if (o >= 192) continue;
        const float sc = bn_g[o] * rsqrtf(bn_v[o] + 1e-5f);
        const float sh = bn_b[o] - bn_m[o] * sc;
        float* op = out + (size_t)(bb * 192 + o) * HWPIX + (size_t)hb * 256;
#pragma unroll
        for (int mt = 0; mt < 4; ++mt) {
#pragma unroll
            for (int reg = 0; reg < 4; ++reg) {
                const int wq = w0 + wm + mt * 16 + quad * 4 + reg;
                op[wq] = fmaxf(acc[mt][nt][reg] * sc + sh, 0.f);
            }
        }
    }
}

// ---------------- per-token LN stats (mean, rstd) from bf16 rows of 128
__global__ __launch_bounds__(256)
void stats_kernel(const u16* __restrict__ X, float* __restrict__ MR, int ntok)
{
    const int r = blockIdx.x * 4 + (threadIdx.x >> 6);
    const int lane = threadIdx.x & 63;
    if (r >= ntok) return;
    const u16* row = X + (size_t)r * 128;
    const float x0 = b2f(row[lane]), x1 = b2f(row[lane + 64]);
    float s = x0 + x1;
#pragma unroll
    for (int off = 32; off; off >>= 1) s += __shfl_xor(s, off);
    const float m = s * (1.f / 128.f);
    const float e0 = x0 - m, e1 = x1 - m;
    float v = e0 * e0 + e1 * e1;
#pragma unroll
    for (int off = 32; off; off >>= 1) v += __shfl_xor(v, off);
    if (lane == 0) { MR[2 * r] = m; MR[2 * r + 1] = rsqrtf(v * (1.f / 128.f) + 1e-5f); }
}

__global__ __launch_bounds__(256)
void kv_stats_kernel(const u16* __restrict__ I, const int* __restrict__ idx,
                     float* __restrict__ MRKV)
{
    const int r = blockIdx.x * 4 + (threadIdx.x >> 6);
    const int lane = threadIdx.x & 63;
    if (r >= 65536) return;
    const int n = r >> 7;
    const int w = idx[r] & 255;
    const u16* row = I + (size_t)(n * 256 + w) * 128;
    const float x0 = b2f(row[lane]), x1 = b2f(row[lane + 64]);
    float s = x0 + x1;
#pragma unroll
    for (int off = 32; off; off >>= 1) s += __shfl_xor(s, off);
    const float m = s * (1.f / 128.f);
    const float e0 = x0 - m, e1 = x1 - m;
    float v = e0 * e0 + e1 * e1;
#pragma unroll
    for (int off = 32; off; off >>= 1) v += __shfl_xor(v, off);
    if (lane == 0) { MRKV[2 * r] = m; MRKV[2 * r + 1] = rsqrtf(v * (1.f / 128.f) + 1e-5f); }
}

// ---------------- score MLP + deterministic top-128 (rank = lax.top_k position)
__global__ __launch_bounds__(256)
void score_select_kernel(const u16* __restrict__ radS, const u16* __restrict__ imgS,
                         const float* __restrict__ Ws1, const float* __restrict__ bs1,
                         const float* __restrict__ Ws2, const float* __restrict__ bs2,
                         int* __restrict__ idx)
{
    __shared__ float WT[256][64];
    const int tid = threadIdx.x, n = blockIdx.x;
    for (int i = tid; i < 16384; i += 256) { const int j = i >> 8, c = i & 255; WT[c][j] = Ws1[i]; }
    __syncthreads();
    float acc[64];
#pragma unroll
    for (int j = 0; j < 64; ++j) acc[j] = 0.f;
    const int t = n * WSEQ + tid;
    const u16* r0 = radS + (size_t)t * 128;
    const u16* r1 = imgS + (size_t)t * 128;
    for (int c = 0; c < 128; ++c) {
        const float v = b2f(r0[c]);
#pragma unroll
        for (int j = 0; j < 64; ++j) acc[j] += v * WT[c][j];
    }
    for (int c = 0; c < 128; ++c) {
        const float v = b2f(r1[c]);
#pragma unroll
        for (int j = 0; j < 64; ++j) acc[j] += v * WT[128 + c][j];
    }
    float s = bs2[0];
#pragma unroll
    for (int j = 0; j < 64; ++j) s += fmaxf(acc[j] + bs1[j], 0.f) * Ws2[j];
    __syncthreads();
    float* sc = &WT[0][0];
    sc[tid] = s;
    __syncthreads();
    int rank = 0;
    for (int j = 0; j < 256; ++j) {
        const float sj = sc[j];
        rank += (sj > s) || (sj == s && j < tid);
    }
    if (rank < 128) idx[n * 128 + rank] = tid;
}

// ---------------- attention: block = (n, head); in-place ao over qh (bf16)
__global__ __launch_bounds__(256)
void attn_kernel(u16* __restrict__ qh, const u16* __restrict__ khvh)
{
    __shared__ float Ks[128 * 16];
    __shared__ float Vs[128 * 16];
    const int n = blockIdx.x >> 3, hd = blockIdx.x & 7;
    const int tid = threadIdx.x;
    {
        const int d = tid & 15, ktb = tid >> 4;
#pragma unroll
        for (int p = 0; p < 8; ++p) {
            const int kt = ktb + p * 16;
            const u16* src = khvh + (size_t)(n * 128 + kt) * 256 + hd * 16 + d;
            Ks[kt * 16 + d] = b2f(src[0]);
            Vs[kt * 16 + d] = b2f(src[128]);
        }
    }
    __syncthreads();
    const int t = n * WSEQ + tid;
    u16* qp = qh + (size_t)t * 128 + hd * 16;
    float q[16];
#pragma unroll
    for (int d = 0; d < 16; ++d) q[d] = b2f(qp[d]);
    float m = -1e30f, l = 0.f;
    float acc[16];
#pragma unroll
    for (int d = 0; d < 16; ++d) acc[d] = 0.f;
    for (int kt = 0; kt < 128; ++kt) {
        const float* kr = &Ks[kt * 16];
        float s = 0.f;
#pragma unroll
        for (int d = 0; d < 16; ++d) s += q[d] * kr[d];
        s *= 0.25f;
        const float mn = fmaxf(m, s);
        const float corr = __expf(m - mn);
        const float p = __expf(s - mn);
        l = l * corr + p;
        const float* vr = &Vs[kt * 16];
#pragma unroll
        for (int d = 0; d < 16; ++d) acc[d] = acc[d] * corr + p * vr[d];
        m = mn;
    }
    const float inv = 1.f / l;
#pragma unroll
    for (int d = 0; d < 16; ++d) qp[d] = f2b(acc[d] * inv);
}

// ---------------- depthwise causal conv (DC=4) + silu, IN PLACE over x (bf16)
__global__ __launch_bounds__(256)
void dwconv_kernel(u16* __restrict__ x, const float* __restrict__ kw,
                   const float* __restrict__ bdw)
{
    const int di = threadIdx.x;
    const int n = blockIdx.x;
    const float k0 = kw[di * 4 + 0], k1 = kw[di * 4 + 1];
    const float k2 = kw[di * 4 + 2], k3 = kw[di * 4 + 3];
    const float bb = bdw[di];
    float x3 = 0.f, x2 = 0.f, x1 = 0.f;
    for (int w = 0; w < 256; ++w) {
        const size_t o = (size_t)(n * WSEQ + w) * 256 + di;
        const float x0 = b2f(x[o]);
        const float v = x3 * k0 + x2 * k1 + x1 * k2 + x0 * k3 + bb;
        x[o] = f2b(v * (1.f / (1.f + __expf(-v))));
        x3 = x2; x2 = x1; x1 = x0;
    }
}

// ---------------- bidirectional selective scan (one token-half per call)
__global__ __launch_bounds__(256)
void scan_kernel(const u16* __restrict__ xs, const u16* __restrict__ dt,
                 const u16* __restrict__ btct, const float* __restrict__ A_log,
                 const float* __restrict__ Dp, const u16* __restrict__ z,
                 u16* __restrict__ yf)
{
    __shared__ float Bs[256][16];
    __shared__ float Cs[256][16];
    const int di = threadIdx.x, n = blockIdx.x;
    for (int i = di; i < 256 * 32; i += 256) {
        const int w = i >> 5, c = i & 31;
        const float v = b2f(btct[(size_t)(n * WSEQ + w) * 32 + c]);
        if (c < 16) Bs[w][c] = v; else Cs[w][c - 16] = v;
    }
    __syncthreads();
    float a[16];
#pragma unroll
    for (int s = 0; s < 16; ++s) a[s] = -__expf(A_log[di * 16 + s]);
    const float dpv = Dp[di];
    float h[16];
#pragma unroll
    for (int s = 0; s < 16; ++s) h[s] = 0.f;
    for (int w = 0; w < 256; ++w) {
        const size_t t = (size_t)(n * WSEQ + w);
        const float dtv = b2f(dt[t * 256 + di]);
        const float xv = b2f(xs[t * 256 + di]);
        const float dx = dtv * xv;
        float yv = 0.f;
#pragma unroll
        for (int s = 0; s < 16; ++s) {
            const float e = __expf(dtv * a[s]);
            h[s] = e * h[s] + dx * Bs[w][s];
            yv += h[s] * Cs[w][s];
        }
        yf[t * 256 + di] = f2b(yv);
    }
#pragma unroll
    for (int s = 0; s < 16; ++s) h[s] = 0.f;
    for (int w = 255; w >= 0; --w) {
        const size_t t = (size_t)(n * WSEQ + w);
        const float dtv = b2f(dt[t * 256 + di]);
        const float xv = b2f(xs[t * 256 + di]);
        const float dx = dtv * xv;
        float yv = 0.f;
#pragma unroll
        for (int s = 0; s < 16; ++s) {
            const float e = __expf(dtv * a[s]);
            h[s] = e * h[s] + dx * Bs[w][s];
            yv += h[s] * Cs[w][s];
        }
        const float zv = b2f(z[t * 256 + di]);
        const float silz = zv * (1.f / (1.f + __expf(-zv)));
        const float tot = b2f(yf[t * 256 + di]) + yv + dpv * xv;
        yf[t * 256 + di] = f2b(tot * silz);
    }
}

// ---------------- hmb <- gamma*rad3 + gammah*hmb (bf16, in place)
__global__ __launch_bounds__(256)
void precomb_kernel(const u16* __restrict__ rad3, u16* __restrict__ hmb,
                    const float* __restrict__ gamma, const float* __restrict__ gammah)
{
    const size_t i = (size_t)blockIdx.x * 256 + threadIdx.x;
    hmb[i] = f2b(gamma[0] * b2f(rad3[i]) + gammah[0] * b2f(hmb[i]));
}

// ---------------- gate + radar_enh + assemble fuse_in (bf16, P x 192)
__global__ __launch_bounds__(256)
void gate_kernel(const float* __restrict__ radar, const float* __restrict__ image,
                 const float* __restrict__ Wg, const float* __restrict__ bg,
                 const u16* __restrict__ dcomb, u16* __restrict__ fin)
{
    __shared__ float WT[192][64];
    const int tid = threadIdx.x;
    const int bh = blockIdx.x;
    const int b = bh >> 8, h = bh & 255;
    for (int i = tid; i < 64 * 192; i += 256) { const int o = i / 192, c = i % 192; WT[c][o] = Wg[i]; }
    __syncthreads();
    float acc[64];
#pragma unroll
    for (int o = 0; o < 64; ++o) acc[o] = 0.f;
    const size_t rbase = (size_t)b * 64 * HWPIX + (size_t)h * 256 + tid;
    const size_t ibase = (size_t)b * 128 * HWPIX + (size_t)h * 256 + tid;
    for (int c = 0; c < 64; ++c) {
        const float v = radar[rbase + (size_t)c * HWPIX];
#pragma unroll
        for (int o = 0; o < 64; ++o) acc[o] += v * WT[c][o];
    }
    for (int c = 0; c < 128; ++c) {
        const float v = image[ibase + (size_t)c * HWPIX];
#pragma unroll
        for (int o = 0; o < 64; ++o) acc[o] += v * WT[64 + c][o];
    }
    const float wm = fmaxf(1.f - 0.7f * (float)h * (1.f / 255.f), 0.3f);
    const size_t t = (size_t)bh * 256 + tid;
    u16* fo = fin + t * 192;
    for (int o = 0; o < 64; ++o) {
        const float gate = wm / (1.f + __expf(-(acc[o] + bg[o])));
        fo[o] = f2b(radar[rbase + (size_t)o * HWPIX] + gate * b2f(dcomb[t * 64 + o]));
    }
    for (int c = 0; c < 128; ++c)
        fo[64 + c] = f2b(image[ibase + (size_t)c * HWPIX]);
}

// ---------------- Wfuse (o,c,kh,kw) fp32 -> Wc[kk][o][c] bf16
__global__ __launch_bounds__(256)
void wprep_kernel(const float* __restrict__ Wfuse, u16* __restrict__ Wc)
{
    const int i = blockIdx.x * 256 + threadIdx.x;
    if (i >= 9 * 192 * 192) return;
    const int kk = i / 36864, r = i % 36864;
    const int o = r / 192, c = r % 192;
    Wc[i] = f2b(Wfuse[o * 1728 + c * 9 + kk]);
}

// ---------------------------------------------------------------------------
extern "C" void kernel_launch(void* const* d_in, const int* in_sizes, int n_in,
                              void* d_out, int out_size, void* d_ws, size_t ws_size,
                              hipStream_t stream)
{
    const float* image  = (const float*)d_in[0];
    const float* radar  = (const float*)d_in[1];
    const float* W_img  = (const float*)d_in[2];
    const float* W_rad  = (const float*)d_in[3];
    const float* g_q    = (const float*)d_in[4];
    const float* b_q    = (const float*)d_in[5];
    const float* g_kv   = (const float*)d_in[6];
    const float* b_kv   = (const float*)d_in[7];
    const float* g2     = (const float*)d_in[8];
    const float* b2     = (const float*)d_in[9];
    const float* Ws1    = (const float*)d_in[10];
    const float* bs1    = (const float*)d_in[11];
    const float* Ws2    = (const float*)d_in[12];
    const float* bs2    = (const float*)d_in[13];
    const float* Wqkv   = (const float*)d_in[14];
    const float* bqkv   = (const float*)d_in[15];
    const float* Wo     = (const float*)d_in[16];
    const float* bo     = (const float*)d_in[17];
    const float* Wf1    = (const float*)d_in[18];
    const float* bf1    = (const float*)d_in[19];
    const float* Wf2    = (const float*)d_in[20];
    const float* bf2    = (const float*)d_in[21];
    const float* W_delta= (const float*)d_in[22];
    const float* gamma  = (const float*)d_in[23];
    const float* gammah = (const float*)d_in[24];
    const float* Wg     = (const float*)d_in[25];
    const float* bg     = (const float*)d_in[26];
    const float* Wfuse  = (const float*)d_in[27];
    const float* bn_g   = (const float*)d_in[28];
    const float* bn_b   = (const float*)d_in[29];
    const float* bn_m   = (const float*)d_in[30];
    const float* bn_v   = (const float*)d_in[31];
    const float* W_hin  = (const float*)d_in[32];
    const float* conv_dw= (const float*)d_in[33];
    const float* b_dw   = (const float*)d_in[34];
    const float* W_dt   = (const float*)d_in[35];
    const float* b_dt   = (const float*)d_in[36];
    const float* W_Bp   = (const float*)d_in[37];
    const float* W_Cp   = (const float*)d_in[38];
    const float* A_log  = (const float*)d_in[39];
    const float* Dp     = (const float*)d_in[40];
    const float* W_hout = (const float*)d_in[41];
    float* out = (float*)d_out;

    // ---- workspace (ushort elems), ~195 MiB ----
    u16* wsu = (u16*)d_ws;
    u16* R = wsu;                      // radS -> rad2 -> rad3
    u16* I = wsu + 16777216u;          // imgS; later dcomb
    u16* U = wsu + 33554432u;          // x -> xs -> fuse_in
    u16* V = wsu + 67108864u;          // z
    u16* Wc = wsu + 100663296u;        // 331,776 bf16 (conv weights, [kk][o][c])
    float* ftail = (float*)(wsu + 100995072u);
    float* MR    = ftail;              // 262,144
    float* MRKV  = ftail + 262144u;    // 131,072
    int*   IDX   = (int*)(ftail + 393216u);  // 65,536

    // ---- d_out as ushort scratch (50,331,648 elems) ----
    u16* ob  = (u16*)d_out;
    u16* QH  = ob;                     // P*128
    u16* KVH = ob + 16777216u;         // 65536*256
    u16* T1  = ob;                     // per-half FFN hidden 65536*512
    u16* DT  = ob;                     // per-half 65536*256
    u16* BC  = ob + 16777216u;         // per-half 65536*32
    u16* Y   = ob + 18874368u;         // per-half 65536*256
    u16* HMB = ob + 35651584u;         // per-half 65536*128
    u16* DC  = I;                      // dcomb P*64 (imgS dead)

    wprep_kernel<<<1296, 256, 0, stream>>>(Wfuse, Wc);

    // conv1x1 to token-major bf16
    mgemm<AM_NCHW, EP_NONE><<<dim3(1024, 1), 256, 0, stream>>>(image, nullptr, nullptr, nullptr, nullptr, nullptr, 128, 128, W_img, nullptr, I, 128, 128);
    mgemm<AM_NCHW, EP_NONE><<<dim3(1024, 1), 256, 0, stream>>>(radar, nullptr, nullptr, nullptr, nullptr, nullptr,  64,  64, W_rad, nullptr, R, 128, 128);

    // scoring + top-128
    score_select_kernel<<<512, 256, 0, stream>>>(R, I, Ws1, bs1, Ws2, bs2, IDX);

    // LN stats
    stats_kernel<<<32768, 256, 0, stream>>>(R, MR, PTOK);
    kv_stats_kernel<<<16384, 256, 0, stream>>>(I, IDX, MRKV);

    // qh = LN(R)@Wq^T + bq ; khvh = LN(gather(I))@[Wk;Wv]^T + [bk;bv]
    mgemm<AM_LN,  EP_NONE><<<dim3(1024, 1), 256, 0, stream>>>(R, nullptr, nullptr, MR, g_q, b_q, 128, 0, Wqkv, bqkv, QH, 128, 128);
    mgemm<AM_LNG, EP_NONE><<<dim3(512, 2), 256, 0, stream>>>(I, nullptr, IDX, MRKV, g_kv, b_kv, 128, 0, Wqkv + 16384, bqkv + 128, KVH, 256, 256);

    // attention in place; rad2 = R + ao@Wo^T + bo
    attn_kernel<<<4096, 256, 0, stream>>>(QH, KVH);
    mgemm<AM_TOK, EP_RES><<<dim3(1024, 1), 256, 0, stream>>>(QH, nullptr, nullptr, nullptr, nullptr, nullptr, 128, 0, Wo, bo, R, 128, 128);

    // FFN (LN folded), hidden chunked through d_out in 2 halves
    stats_kernel<<<32768, 256, 0, stream>>>(R, MR, PTOK);
    for (int hfl = 0; hfl < 2; ++hfl) {
        const size_t off = (size_t)hfl * 65536u;
        mgemm<AM_LN,  EP_RELU><<<dim3(512, 4), 256, 0, stream>>>(R + off * 128, nullptr, nullptr, MR + off * 2, g2, b2, 128, 0, Wf1, bf1, T1, 512, 512);
        mgemm<AM_TOK, EP_RES ><<<dim3(512, 1), 256, 0, stream>>>(T1, nullptr, nullptr, nullptr, nullptr, nullptr, 512, 0, Wf2, bf2, R + off * 128, 128, 128);
    }

    // xz: x -> U, z -> V  (A = [rad3 ; imgS], K=256)
    mgemm<AM_CAT, EP_NONE><<<dim3(1024, 2), 256, 0, stream>>>(R, I, nullptr, nullptr, nullptr, nullptr, 256, 0, W_hin, nullptr, U, 256, 256);
    mgemm<AM_CAT, EP_NONE><<<dim3(1024, 2), 256, 0, stream>>>(R, I, nullptr, nullptr, nullptr, nullptr, 256, 0, W_hin + 65536, nullptr, V, 256, 256);

    // depthwise causal conv + silu, in place: U: x -> xs
    dwconv_kernel<<<512, 256, 0, stream>>>(U, conv_dw, b_dw);

    // SSM in 2 token-halves through d_out
    for (int hfl = 0; hfl < 2; ++hfl) {
        const size_t off = (size_t)hfl * 65536u;
        u16* xs = U + off * 256;
        u16* z  = V + off * 256;
        mgemm<AM_TOK, EP_SP  ><<<dim3(512, 2), 256, 0, stream>>>(xs, nullptr, nullptr, nullptr, nullptr, nullptr, 256, 0, W_dt, b_dt, DT, 256, 256);
        mgemm<AM_TOK, EP_NONE><<<dim3(512, 1), 256, 0, stream>>>(xs, nullptr, nullptr, nullptr, nullptr, nullptr, 256, 0, W_Bp, nullptr, BC, 16, 32);
        mgemm<AM_TOK, EP_NONE><<<dim3(512, 1), 256, 0, stream>>>(xs, nullptr, nullptr, nullptr, nullptr, nullptr, 256, 0, W_Cp, nullptr, BC + 16, 16, 32);
        scan_kernel<<<256, 256, 0, stream>>>(xs, DT, BC, A_log, Dp, z, Y);
        mgemm<AM_TOK, EP_NONE><<<dim3(512, 1), 256, 0, stream>>>(Y, nullptr, nullptr, nullptr, nullptr, nullptr, 256, 0, W_hout, nullptr, HMB, 128, 128);
        precomb_kernel<<<32768, 256, 0, stream>>>(R + off * 128, HMB, gamma, gammah);
        mgemm<AM_TOK, EP_NONE><<<dim3(512, 1), 256, 0, stream>>>(HMB, nullptr, nullptr, nullptr, nullptr, nullptr, 128, 0, W_delta, nullptr, DC + off * 64, 64, 64);
    }

    // gate + radar_enh + fuse_in (U, xs dead)
    gate_kernel<<<512, 256, 0, stream>>>(radar, image, Wg, bg, DC, U);

    // final 3x3 conv (implicit MFMA GEMM) + BN + relu -> d_out fp32 NCHW
    conv3x3_mfma<<<dim3(1024, 2), 256, 0, stream>>>(U, Wc, bn_g, bn_b, bn_m, bn_v, out);
}

// Round 5
// 1998.122 us; speedup vs baseline: 2.8247x; 1.1322x over previous
//
#include <hip/hip_runtime.h>
#include <hip/hip_bf16.h>
#include <cstddef>

// ---------------------------------------------------------------------------
// FusionAfterBEVSEDirect — bf16 storage, MFMA compute (round 5)
// Round-5 change: direction-parallel selective scan (fwd/bwd in separate
// blocks, finalize folded into the W_hout GEMM A-staging), Bt/Ct merged.
// ---------------------------------------------------------------------------

#define PTOK   131072
#define WSEQ   256
#define HWPIX  65536

typedef unsigned short u16;
typedef unsigned int   u32;
typedef __bf16 bf16x8 __attribute__((ext_vector_type(8)));
typedef float  f32x4  __attribute__((ext_vector_type(4)));

__device__ __forceinline__ float b2f(u16 u) { return __uint_as_float((u32)u << 16); }
__device__ __forceinline__ u16   f2b(float f) {
    u32 x = __float_as_uint(f);
    return (u16)((x + 0x7fffu + ((x >> 16) & 1u)) >> 16);
}
__device__ __forceinline__ u32 pk2(float a, float b) {
    return (u32)f2b(a) | ((u32)f2b(b) << 16);
}
__device__ __forceinline__ void unpack8(uint4 p, float* v) {
    const u32 a[4] = {p.x, p.y, p.z, p.w};
#pragma unroll
    for (int q = 0; q < 4; ++q) {
        v[2 * q]     = b2f((u16)(a[q] & 0xffffu));
        v[2 * q + 1] = b2f((u16)(a[q] >> 16));
    }
}
__device__ __forceinline__ void load32(const u16* p, float* v) {
    uint4 a = *(const uint4*)p, b = *(const uint4*)(p + 8);
    uint4 c = *(const uint4*)(p + 16), d = *(const uint4*)(p + 24);
    unpack8(a, v); unpack8(b, v + 8); unpack8(c, v + 16); unpack8(d, v + 24);
}

constexpr int AM_NCHW = 0, AM_TOK = 1, AM_LN = 2, AM_LNG = 3, AM_CAT = 4, AM_FIN = 5;
constexpr int EP_NONE = 0, EP_RELU = 1, EP_RES = 2, EP_SP = 3;

// ---------------- MFMA GEMM: C(M,O) = epi(A(M,K) @ Bw(O,K)^T + bias)
// tile 128x128, 4 waves (2x2 of 64x64), K-step 64, bf16 in/out, fp32 acc.
template<int AM, int EPI>
__global__ __launch_bounds__(256)
void mgemm(const void* __restrict__ Apv, const void* __restrict__ Ap2v,
           const void* __restrict__ Ap3v, const void* __restrict__ Ap4v,
           const int* __restrict__ gidx, const float* __restrict__ stats,
           const float* __restrict__ lng, const float* __restrict__ lnb,
           const float* __restrict__ dpv,
           int K, int Cin,
           const float* __restrict__ Bw, const float* __restrict__ Bw2,
           const float* __restrict__ bias,
           u16* __restrict__ Cout, int O, int Ostride)
{
    __shared__ u16 Als[128 * 72];
    __shared__ u16 Bls[128 * 72];
    const int tid = threadIdx.x;
    const int t0 = blockIdx.x * 128;
    const int o0 = blockIdx.y * 128;
    const int lane = tid & 63, wv = tid >> 6;
    const int wm = (wv & 1) * 64, wn = (wv >> 1) * 64;
    const int fc = lane & 15, quad = lane >> 4;

    f32x4 acc[4][4];
#pragma unroll
    for (int i = 0; i < 4; ++i)
#pragma unroll
        for (int j = 0; j < 4; ++j) acc[i][j] = {0.f, 0.f, 0.f, 0.f};

    const int srow = tid >> 1;             // 0..127
    const int sseg = (tid & 1) * 32;       // k sub-offset

    float mrow = 0.f, rrow = 1.f;
    int grow = t0 + srow;
    if (AM == AM_LN) { mrow = stats[2 * (t0 + srow)]; rrow = stats[2 * (t0 + srow) + 1]; }
    if (AM == AM_LNG) {
        const int ar = t0 + srow;
        grow = (ar >> 7) * 256 + (gidx[ar] & 255);
        mrow = stats[2 * ar]; rrow = stats[2 * ar + 1];
    }

    for (int kc0 = 0; kc0 < K; kc0 += 64) {
        // ---- stage A ----
        if (AM == AM_NCHW) {
            const float* Af = (const float*)Apv;
            const int tl = tid & 127, cg = (tid >> 7) * 32;
            const int t = t0 + tl;
            const size_t base = (size_t)(t >> 16) * (size_t)Cin * HWPIX + (size_t)(t & (HWPIX - 1));
#pragma unroll 8
            for (int p = 0; p < 32; ++p) {
                const int c = kc0 + cg + p;
                Als[tl * 72 + cg + p] = f2b(Af[base + (size_t)c * HWPIX]);
            }
        } else if (AM == AM_FIN) {
            const int cb = kc0 + sseg;
            const size_t base = (size_t)(t0 + srow) * 256 + cb;
            float vy[32], vb[32], vx[32], vz[32];
            load32((const u16*)Apv  + base, vy);
            load32((const u16*)Ap2v + base, vb);
            load32((const u16*)Ap3v + base, vx);
            load32((const u16*)Ap4v + base, vz);
            float v[32];
#pragma unroll
            for (int p = 0; p < 32; ++p) {
                const float dp = dpv[cb + p];
                const float zz = vz[p];
                const float tot = vy[p] + vb[p] + dp * vx[p];
                v[p] = tot * (zz / (1.f + __expf(-zz)));
            }
            uint4 q0, q1, q2, q3;
            q0.x = pk2(v[0], v[1]);   q0.y = pk2(v[2], v[3]);   q0.z = pk2(v[4], v[5]);   q0.w = pk2(v[6], v[7]);
            q1.x = pk2(v[8], v[9]);   q1.y = pk2(v[10], v[11]); q1.z = pk2(v[12], v[13]); q1.w = pk2(v[14], v[15]);
            q2.x = pk2(v[16], v[17]); q2.y = pk2(v[18], v[19]); q2.z = pk2(v[20], v[21]); q2.w = pk2(v[22], v[23]);
            q3.x = pk2(v[24], v[25]); q3.y = pk2(v[26], v[27]); q3.z = pk2(v[28], v[29]); q3.w = pk2(v[30], v[31]);
            uint4* dst = (uint4*)&Als[srow * 72 + sseg];
            dst[0] = q0; dst[1] = q1; dst[2] = q2; dst[3] = q3;
        } else {
            const u16* src; int rs, cb, row;
            if (AM == AM_CAT) {
                src = (kc0 & 128) ? (const u16*)Ap2v : (const u16*)Apv;
                rs = 128; cb = (kc0 & 127) + sseg; row = t0 + srow;
            } else if (AM == AM_LNG) {
                src = (const u16*)Apv; rs = 128; cb = kc0 + sseg; row = grow;
            } else {
                src = (const u16*)Apv; rs = K; cb = kc0 + sseg; row = t0 + srow;
            }
            const u16* rp = src + (size_t)row * rs + cb;
            uint4 pa = *(const uint4*)rp;
            uint4 pb = *(const uint4*)(rp + 8);
            uint4 pc = *(const uint4*)(rp + 16);
            uint4 pd = *(const uint4*)(rp + 24);
            if (AM == AM_LN || AM == AM_LNG) {
                float v[32];
                unpack8(pa, v); unpack8(pb, v + 8); unpack8(pc, v + 16); unpack8(pd, v + 24);
                const int c0 = cb;
#pragma unroll
                for (int p = 0; p < 32; ++p)
                    v[p] = (v[p] - mrow) * rrow * lng[c0 + p] + lnb[c0 + p];
                uint4 q0, q1, q2, q3;
                q0.x = pk2(v[0], v[1]);   q0.y = pk2(v[2], v[3]);   q0.z = pk2(v[4], v[5]);   q0.w = pk2(v[6], v[7]);
                q1.x = pk2(v[8], v[9]);   q1.y = pk2(v[10], v[11]); q1.z = pk2(v[12], v[13]); q1.w = pk2(v[14], v[15]);
                q2.x = pk2(v[16], v[17]); q2.y = pk2(v[18], v[19]); q2.z = pk2(v[20], v[21]); q2.w = pk2(v[22], v[23]);
                q3.x = pk2(v[24], v[25]); q3.y = pk2(v[26], v[27]); q3.z = pk2(v[28], v[29]); q3.w = pk2(v[30], v[31]);
                pa = q0; pb = q1; pc = q2; pd = q3;
            }
            uint4* dst = (uint4*)&Als[srow * 72 + sseg];
            dst[0] = pa; dst[1] = pb; dst[2] = pc; dst[3] = pd;
        }
        // ---- stage B (fp32 weights -> bf16; optional row-split Bw/Bw2) ----
        {
            const int og = o0 + srow;
            const bool ok = og < O;
            uint4 q0 = {0,0,0,0}, q1 = {0,0,0,0}, q2 = {0,0,0,0}, q3 = {0,0,0,0};
            if (ok) {
                const float* rp;
                if (Bw2 && og >= 16) rp = Bw2 + (size_t)(og - 16) * K + kc0 + sseg;
                else                 rp = Bw  + (size_t)og * K + kc0 + sseg;
                float v[32];
#pragma unroll
                for (int p = 0; p < 8; ++p) {
                    const float4 f = *(const float4*)(rp + p * 4);
                    v[p * 4 + 0] = f.x; v[p * 4 + 1] = f.y; v[p * 4 + 2] = f.z; v[p * 4 + 3] = f.w;
                }
                q0.x = pk2(v[0], v[1]);   q0.y = pk2(v[2], v[3]);   q0.z = pk2(v[4], v[5]);   q0.w = pk2(v[6], v[7]);
                q1.x = pk2(v[8], v[9]);   q1.y = pk2(v[10], v[11]); q1.z = pk2(v[12], v[13]); q1.w = pk2(v[14], v[15]);
                q2.x = pk2(v[16], v[17]); q2.y = pk2(v[18], v[19]); q2.z = pk2(v[20], v[21]); q2.w = pk2(v[22], v[23]);
                q3.x = pk2(v[24], v[25]); q3.y = pk2(v[26], v[27]); q3.z = pk2(v[28], v[29]); q3.w = pk2(v[30], v[31]);
            }
            uint4* dst = (uint4*)&Bls[srow * 72 + sseg];
            dst[0] = q0; dst[1] = q1; dst[2] = q2; dst[3] = q3;
        }
        __syncthreads();
#pragma unroll
        for (int kc = 0; kc < 64; kc += 32) {
            bf16x8 aF[4], bF[4];
#pragma unroll
            for (int mt = 0; mt < 4; ++mt)
                aF[mt] = *(const bf16x8*)&Als[(wm + mt * 16 + fc) * 72 + kc + quad * 8];
#pragma unroll
            for (int nt = 0; nt < 4; ++nt)
                bF[nt] = *(const bf16x8*)&Bls[(wn + nt * 16 + fc) * 72 + kc + quad * 8];
#pragma unroll
            for (int mt = 0; mt < 4; ++mt)
#pragma unroll
                for (int nt = 0; nt < 4; ++nt)
                    acc[mt][nt] = __builtin_amdgcn_mfma_f32_16x16x32_bf16(aF[mt], bF[nt], acc[mt][nt], 0, 0, 0);
        }
        __syncthreads();
    }

#pragma unroll
    for (int nt = 0; nt < 4; ++nt) {
        const int o = o0 + wn + nt * 16 + fc;
        if (o >= O) continue;
        const float bv = bias ? bias[o] : 0.f;
#pragma unroll
        for (int mt = 0; mt < 4; ++mt) {
#pragma unroll
            for (int reg = 0; reg < 4; ++reg) {
                const int t = t0 + wm + mt * 16 + quad * 4 + reg;
                float v = acc[mt][nt][reg] + bv;
                if (EPI == EP_RELU) v = fmaxf(v, 0.f);
                if (EPI == EP_SP)   v = fmaxf(v, 0.f) + log1pf(expf(-fabsf(v)));
                u16* dst = Cout + (size_t)t * Ostride + o;
                if (EPI == EP_RES)  v += b2f(*dst);
                *dst = f2b(v);
            }
        }
    }
}

// ---------------- conv3x3 as implicit MFMA GEMM; K = 9*192 = 1728
__global__ __launch_bounds__(256)
void conv3x3_mfma(const u16* __restrict__ fin, const u16* __restrict__ Wc,
                  const float* __restrict__ bn_g, const float* __restrict__ bn_b,
                  const float* __restrict__ bn_m, const float* __restrict__ bn_v,
                  float* __restrict__ out)
{
    __shared__ u16 Als[128 * 72];
    __shared__ u16 Bls[128 * 72];
    const int tid = threadIdx.x;
    const int t0 = blockIdx.x * 128;
    const int o0 = blockIdx.y * 128;
    const int lane = tid & 63, wv = tid >> 6;
    const int wm = (wv & 1) * 64, wn = (wv >> 1) * 64;
    const int fc = lane & 15, quad = lane >> 4;

    f32x4 acc[4][4];
#pragma unroll
    for (int i = 0; i < 4; ++i)
#pragma unroll
        for (int j = 0; j < 4; ++j) acc[i][j] = {0.f, 0.f, 0.f, 0.f};

    const int srow = tid >> 1;
    const int sseg = (tid & 1) * 32;
    const int t = t0 + srow;
    const int h = (t >> 8) & 255, w = t & 255;

    for (int chunk = 0; chunk < 27; ++chunk) {
        const int kk = chunk / 3;
        const int c0 = (chunk % 3) * 64;
        const int kh = kk / 3, kw = kk % 3;
        {
            const int hh = h + kh - 1, ww = w + kw - 1;
            const bool ok = ((unsigned)hh < 256u) && ((unsigned)ww < 256u);
            uint4 p0 = {0,0,0,0}, p1 = {0,0,0,0}, p2 = {0,0,0,0}, p3 = {0,0,0,0};
            if (ok) {
                const u16* rp = fin + (size_t)(t + (kh - 1) * 256 + (kw - 1)) * 192 + c0 + sseg;
                p0 = *(const uint4*)rp; p1 = *(const uint4*)(rp + 8);
                p2 = *(const uint4*)(rp + 16); p3 = *(const uint4*)(rp + 24);
            }
            uint4* dst = (uint4*)&Als[srow * 72 + sseg];
            dst[0] = p0; dst[1] = p1; dst[2] = p2; dst[3] = p3;
        }
        {
            const int orow = srow;
            const bool ok = (o0 + orow) < 192;
            uint4 p0 = {0,0,0,0}, p1 = {0,0,0,0}, p2 = {0,0,0,0}, p3 = {0,0,0,0};
            if (ok) {
                const u16* rp = Wc + (size_t)kk * 36864 + (size_t)(o0 + orow) * 192 + c0 + sseg;
                p0 = *(const uint4*)rp; p1 = *(const uint4*)(rp + 8);
                p2 = *(const uint4*)(rp + 16); p3 = *(const uint4*)(rp + 24);
            }
            uint4* dst = (uint4*)&Bls[orow * 72 + sseg];
            dst[0] = p0; dst[1] = p1; dst[2] = p2; dst[3] = p3;
        }
        __syncthreads();
#pragma unroll
        for (int kc = 0; kc < 64; kc += 32) {
            bf16x8 aF[4], bF[4];
#pragma unroll
            for (int mt = 0; mt < 4; ++mt)
                aF[mt] = *(const bf16x8*)&Als[(wm + mt * 16 + fc) * 72 + kc + quad * 8];
#pragma unroll
            for (int nt = 0; nt < 4; ++nt)
                bF[nt] = *(const bf16x8*)&Bls[(wn + nt * 16 + fc) * 72 + kc + quad * 8];
#pragma unroll
            for (int mt = 0; mt < 4; ++mt)
#pragma unroll
                for (int nt = 0; nt < 4; ++nt)
                    acc[mt][nt] = __builtin_amdgcn_mfma_f32_16x16x32_bf16(aF[mt], bF[nt], acc[mt][nt], 0, 0, 0);
        }
        __syncthreads();
    }

    const int bb = t0 >> 16, hb = (t0 >> 8) & 255, w0 = t0 & 255;
#pragma unroll
    for (int nt = 0; nt < 4; ++nt) {
        const int o = o0 + wn + nt * 16 + fc;
        if (o >= 192) continue;
        const float sc = bn_g[o] * rsqrtf(bn_v[o] + 1e-5f);
        const float sh = bn_b[o] - bn_m[o] * sc;
        float* op = out + (size_t)(bb * 192 + o) * HWPIX + (size_t)hb * 256;
#pragma unroll
        for (int mt = 0; mt < 4; ++mt) {
#pragma unroll
            for (int reg = 0; reg < 4; ++reg) {
                const int wq = w0 + wm + mt * 16 + quad * 4 + reg;
                op[wq] = fmaxf(acc[mt][nt][reg] * sc + sh, 0.f);
            }
        }
    }
}

// ---------------- per-token LN stats (mean, rstd)
__global__ __launch_bounds__(256)
void stats_kernel(const u16* __restrict__ X, float* __restrict__ MR, int ntok)
{
    const int r = blockIdx.x * 4 + (threadIdx.x >> 6);
    const int lane = threadIdx.x & 63;
    if (r >= ntok) return;
    const u16* row = X + (size_t)r * 128;
    const float x0 = b2f(row[lane]), x1 = b2f(row[lane + 64]);
    float s = x0 + x1;
#pragma unroll
    for (int off = 32; off; off >>= 1) s += __shfl_xor(s, off);
    const float m = s * (1.f / 128.f);
    const float e0 = x0 - m, e1 = x1 - m;
    float v = e0 * e0 + e1 * e1;
#pragma unroll
    for (int off = 32; off; off >>= 1) v += __shfl_xor(v, off);
    if (lane == 0) { MR[2 * r] = m; MR[2 * r + 1] = rsqrtf(v * (1.f / 128.f) + 1e-5f); }
}

__global__ __launch_bounds__(256)
void kv_stats_kernel(const u16* __restrict__ I, const int* __restrict__ idx,
                     float* __restrict__ MRKV)
{
    const int r = blockIdx.x * 4 + (threadIdx.x >> 6);
    const int lane = threadIdx.x & 63;
    if (r >= 65536) return;
    const int n = r >> 7;
    const int w = idx[r] & 255;
    const u16* row = I + (size_t)(n * 256 + w) * 128;
    const float x0 = b2f(row[lane]), x1 = b2f(row[lane + 64]);
    float s = x0 + x1;
#pragma unroll
    for (int off = 32; off; off >>= 1) s += __shfl_xor(s, off);
    const float m = s * (1.f / 128.f);
    const float e0 = x0 - m, e1 = x1 - m;
    float v = e0 * e0 + e1 * e1;
#pragma unroll
    for (int off = 32; off; off >>= 1) v += __shfl_xor(v, off);
    if (lane == 0) { MRKV[2 * r] = m; MRKV[2 * r + 1] = rsqrtf(v * (1.f / 128.f) + 1e-5f); }
}

// ---------------- score MLP + deterministic top-128
__global__ __launch_bounds__(256)
void score_select_kernel(const u16* __restrict__ radS, const u16* __restrict__ imgS,
                         const float* __restrict__ Ws1, const float* __restrict__ bs1,
                         const float* __restrict__ Ws2, const float* __restrict__ bs2,
                         int* __restrict__ idx)
{
    __shared__ float WT[256][64];
    const int tid = threadIdx.x, n = blockIdx.x;
    for (int i = tid; i < 16384; i += 256) { const int j = i >> 8, c = i & 255; WT[c][j] = Ws1[i]; }
    __syncthreads();
    float acc[64];
#pragma unroll
    for (int j = 0; j < 64; ++j) acc[j] = 0.f;
    const int t = n * WSEQ + tid;
    const u16* r0 = radS + (size_t)t * 128;
    const u16* r1 = imgS + (size_t)t * 128;
    for (int c = 0; c < 128; ++c) {
        const float v = b2f(r0[c]);
#pragma unroll
        for (int j = 0; j < 64; ++j) acc[j] += v * WT[c][j];
    }
    for (int c = 0; c < 128; ++c) {
        const float v = b2f(r1[c]);
#pragma unroll
        for (int j = 0; j < 64; ++j) acc[j] += v * WT[128 + c][j];
    }
    float s = bs2[0];
#pragma unroll
    for (int j = 0; j < 64; ++j) s += fmaxf(acc[j] + bs1[j], 0.f) * Ws2[j];
    __syncthreads();
    float* sc = &WT[0][0];
    sc[tid] = s;
    __syncthreads();
    int rank = 0;
    for (int j = 0; j < 256; ++j) {
        const float sj = sc[j];
        rank += (sj > s) || (sj == s && j < tid);
    }
    if (rank < 128) idx[n * 128 + rank] = tid;
}

// ---------------- attention: block = (n, head); in-place ao over qh
__global__ __launch_bounds__(256)
void attn_kernel(u16* __restrict__ qh, const u16* __restrict__ khvh)
{
    __shared__ float Ks[128 * 16];
    __shared__ float Vs[128 * 16];
    const int n = blockIdx.x >> 3, hd = blockIdx.x & 7;
    const int tid = threadIdx.x;
    {
        const int d = tid & 15, ktb = tid >> 4;
#pragma unroll
        for (int p = 0; p < 8; ++p) {
            const int kt = ktb + p * 16;
            const u16* src = khvh + (size_t)(n * 128 + kt) * 256 + hd * 16 + d;
            Ks[kt * 16 + d] = b2f(src[0]);
            Vs[kt * 16 + d] = b2f(src[128]);
        }
    }
    __syncthreads();
    const int t = n * WSEQ + tid;
    u16* qp = qh + (size_t)t * 128 + hd * 16;
    float q[16];
#pragma unroll
    for (int d = 0; d < 16; ++d) q[d] = b2f(qp[d]);
    float m = -1e30f, l = 0.f;
    float acc[16];
#pragma unroll
    for (int d = 0; d < 16; ++d) acc[d] = 0.f;
    for (int kt = 0; kt < 128; ++kt) {
        const float* kr = &Ks[kt * 16];
        float s = 0.f;
#pragma unroll
        for (int d = 0; d < 16; ++d) s += q[d] * kr[d];
        s *= 0.25f;
        const float mn = fmaxf(m, s);
        const float corr = __expf(m - mn);
        const float p = __expf(s - mn);
        l = l * corr + p;
        const float* vr = &Vs[kt * 16];
#pragma unroll
        for (int d = 0; d < 16; ++d) acc[d] = acc[d] * corr + p * vr[d];
        m = mn;
    }
    const float inv = 1.f / l;
#pragma unroll
    for (int d = 0; d < 16; ++d) qp[d] = f2b(acc[d] * inv);
}

// ---------------- depthwise causal conv (DC=4) + silu, in place
__global__ __launch_bounds__(256)
void dwconv_kernel(u16* __restrict__ x, const float* __restrict__ kw,
                   const float* __restrict__ bdw)
{
    const int di = threadIdx.x;
    const int n = blockIdx.x;
    const float k0 = kw[di * 4 + 0], k1 = kw[di * 4 + 1];
    const float k2 = kw[di * 4 + 2], k3 = kw[di * 4 + 3];
    const float bb = bdw[di];
    float x3 = 0.f, x2 = 0.f, x1 = 0.f;
    for (int w = 0; w < 256; ++w) {
        const size_t o = (size_t)(n * WSEQ + w) * 256 + di;
        const float x0 = b2f(x[o]);
        const float v = x3 * k0 + x2 * k1 + x1 * k2 + x0 * k3 + bb;
        x[o] = f2b(v * (1.f / (1.f + __expf(-v))));
        x3 = x2; x2 = x1; x1 = x0;
    }
}

// ---------------- selective scan, direction-parallel (grid = 512 per half:
// blocks [0,256) forward -> yf, [256,512) backward -> yb). Finalize happens
// in the W_hout GEMM (AM_FIN).
__global__ __launch_bounds__(256)
void scan_kernel(const u16* __restrict__ xs, const u16* __restrict__ dt,
                 const u16* __restrict__ btct, const float* __restrict__ A_log,
                 u16* __restrict__ yf, u16* __restrict__ yb)
{
    __shared__ float Bs[256][16];
    __shared__ float Cs[256][16];
    const int di = threadIdx.x;
    const int n = blockIdx.x & 255;
    const int dir = blockIdx.x >> 8;
    for (int i = di; i < 256 * 32; i += 256) {
        const int w = i >> 5, c = i & 31;
        const float v = b2f(btct[(size_t)(n * WSEQ + w) * 32 + c]);
        if (c < 16) Bs[w][c] = v; else Cs[w][c - 16] = v;
    }
    __syncthreads();
    float a[16];
#pragma unroll
    for (int s = 0; s < 16; ++s) a[s] = -__expf(A_log[di * 16 + s]);
    float h[16];
#pragma unroll
    for (int s = 0; s < 16; ++s) h[s] = 0.f;
    u16* yo = dir ? yb : yf;
    for (int i = 0; i < 256; ++i) {
        const int w = dir ? 255 - i : i;
        const size_t t = (size_t)(n * WSEQ + w);
        const float dtv = b2f(dt[t * 256 + di]);
        const float xv = b2f(xs[t * 256 + di]);
        const float dx = dtv * xv;
        float yv = 0.f;
#pragma unroll
        for (int s = 0; s < 16; ++s) {
            const float e = __expf(dtv * a[s]);
            h[s] = e * h[s] + dx * Bs[w][s];
            yv += h[s] * Cs[w][s];
        }
        yo[t * 256 + di] = f2b(yv);
    }
}

// ---------------- hmb <- gamma*rad3 + gammah*hmb (bf16, in place)
__global__ __launch_bounds__(256)
void precomb_kernel(const u16* __restrict__ rad3, u16* __restrict__ hmb,
                    const float* __restrict__ gamma, const float* __restrict__ gammah)
{
    const size_t i = (size_t)blockIdx.x * 256 + threadIdx.x;
    hmb[i] = f2b(gamma[0] * b2f(rad3[i]) + gammah[0] * b2f(hmb[i]));
}

// ---------------- gate + radar_enh + assemble fuse_in (bf16, P x 192)
__global__ __launch_bounds__(256)
void gate_kernel(const float* __restrict__ radar, const float* __restrict__ image,
                 const float* __restrict__ Wg, const float* __restrict__ bg,
                 const u16* __restrict__ dcomb, u16* __restrict__ fin)
{
    __shared__ float WT[192][64];
    const int tid = threadIdx.x;
    const int bh = blockIdx.x;
    const int b = bh >> 8, h = bh & 255;
    for (int i = tid; i < 64 * 192; i += 256) { const int o = i / 192, c = i % 192; WT[c][o] = Wg[i]; }
    __syncthreads();
    float acc[64];
#pragma unroll
    for (int o = 0; o < 64; ++o) acc[o] = 0.f;
    const size_t rbase = (size_t)b * 64 * HWPIX + (size_t)h * 256 + tid;
    const size_t ibase = (size_t)b * 128 * HWPIX + (size_t)h * 256 + tid;
    for (int c = 0; c < 64; ++c) {
        const float v = radar[rbase + (size_t)c * HWPIX];
#pragma unroll
        for (int o = 0; o < 64; ++o) acc[o] += v * WT[c][o];
    }
    for (int c = 0; c < 128; ++c) {
        const float v = image[ibase + (size_t)c * HWPIX];
#pragma unroll
        for (int o = 0; o < 64; ++o) acc[o] += v * WT[64 + c][o];
    }
    const float wm = fmaxf(1.f - 0.7f * (float)h * (1.f / 255.f), 0.3f);
    const size_t t = (size_t)bh * 256 + tid;
    u16* fo = fin + t * 192;
    for (int o = 0; o < 64; ++o) {
        const float gate = wm / (1.f + __expf(-(acc[o] + bg[o])));
        fo[o] = f2b(radar[rbase + (size_t)o * HWPIX] + gate * b2f(dcomb[t * 64 + o]));
    }
    for (int c = 0; c < 128; ++c)
        fo[64 + c] = f2b(image[ibase + (size_t)c * HWPIX]);
}

// ---------------- Wfuse (o,c,kh,kw) fp32 -> Wc[kk][o][c] bf16
__global__ __launch_bounds__(256)
void wprep_kernel(const float* __restrict__ Wfuse, u16* __restrict__ Wc)
{
    const int i = blockIdx.x * 256 + threadIdx.x;
    if (i >= 9 * 192 * 192) return;
    const int kk = i / 36864, r = i % 36864;
    const int o = r / 192, c = r % 192;
    Wc[i] = f2b(Wfuse[o * 1728 + c * 9 + kk]);
}

// ---------------------------------------------------------------------------
extern "C" void kernel_launch(void* const* d_in, const int* in_sizes, int n_in,
                              void* d_out, int out_size, void* d_ws, size_t ws_size,
                              hipStream_t stream)
{
    const float* image  = (const float*)d_in[0];
    const float* radar  = (const float*)d_in[1];
    const float* W_img  = (const float*)d_in[2];
    const float* W_rad  = (const float*)d_in[3];
    const float* g_q    = (const float*)d_in[4];
    const float* b_q    = (const float*)d_in[5];
    const float* g_kv   = (const float*)d_in[6];
    const float* b_kv   = (const float*)d_in[7];
    const float* g2     = (const float*)d_in[8];
    const float* b2     = (const float*)d_in[9];
    const float* Ws1    = (const float*)d_in[10];
    const float* bs1    = (const float*)d_in[11];
    const float* Ws2    = (const float*)d_in[12];
    const float* bs2    = (const float*)d_in[13];
    const float* Wqkv   = (const float*)d_in[14];
    const float* bqkv   = (const float*)d_in[15];
    const float* Wo     = (const float*)d_in[16];
    const float* bo     = (const float*)d_in[17];
    const float* Wf1    = (const float*)d_in[18];
    const float* bf1    = (const float*)d_in[19];
    const float* Wf2    = (const float*)d_in[20];
    const float* bf2    = (const float*)d_in[21];
    const float* W_delta= (const float*)d_in[22];
    const float* gamma  = (const float*)d_in[23];
    const float* gammah = (const float*)d_in[24];
    const float* Wg     = (const float*)d_in[25];
    const float* bg     = (const float*)d_in[26];
    const float* Wfuse  = (const float*)d_in[27];
    const float* bn_g   = (const float*)d_in[28];
    const float* bn_b   = (const float*)d_in[29];
    const float* bn_m   = (const float*)d_in[30];
    const float* bn_v   = (const float*)d_in[31];
    const float* W_hin  = (const float*)d_in[32];
    const float* conv_dw= (const float*)d_in[33];
    const float* b_dw   = (const float*)d_in[34];
    const float* W_dt   = (const float*)d_in[35];
    const float* b_dt   = (const float*)d_in[36];
    const float* W_Bp   = (const float*)d_in[37];
    const float* W_Cp   = (const float*)d_in[38];
    const float* A_log  = (const float*)d_in[39];
    const float* Dp     = (const float*)d_in[40];
    const float* W_hout = (const float*)d_in[41];
    float* out = (float*)d_out;

    // ---- workspace (ushort elems), ~195 MiB ----
    u16* wsu = (u16*)d_ws;
    u16* R = wsu;                      // radS -> rad2 -> rad3
    u16* I = wsu + 16777216u;          // imgS -> per-half Yb
    u16* U = wsu + 33554432u;          // x -> xs -> fuse_in
    u16* V = wsu + 67108864u;          // z ; dcomb in [0, 8.4M) after use
    u16* Wc = wsu + 100663296u;        // conv weights [kk][o][c] bf16
    float* ftail = (float*)(wsu + 100995072u);
    float* MR    = ftail;              // 262,144
    float* MRKV  = ftail + 262144u;    // 131,072
    int*   IDX   = (int*)(ftail + 393216u);  // 65,536

    // ---- d_out as ushort scratch (50,331,648 elems) ----
    u16* ob  = (u16*)d_out;
    u16* QH  = ob;                     // P*128
    u16* KVH = ob + 16777216u;         // 65536*256
    u16* T1  = ob;                     // per-half FFN hidden 65536*512
    u16* DT  = ob;                     // per-half 65536*256
    u16* BC  = ob + 16777216u;         // per-half 65536*32
    u16* YF  = ob + 18874368u;         // per-half 65536*256
    u16* HMB = ob + 35651584u;         // per-half 65536*128
    u16* YB  = I;                      // per-half 65536*256 (imgS dead)
    u16* DC  = V;                      // dcomb P*64 (z half-0 dead by then)

    wprep_kernel<<<1296, 256, 0, stream>>>(Wfuse, Wc);

    // conv1x1 to token-major bf16
    mgemm<AM_NCHW, EP_NONE><<<dim3(1024, 1), 256, 0, stream>>>(image, nullptr, nullptr, nullptr, nullptr, nullptr, nullptr, nullptr, nullptr, 128, 128, W_img, nullptr, nullptr, I, 128, 128);
    mgemm<AM_NCHW, EP_NONE><<<dim3(1024, 1), 256, 0, stream>>>(radar, nullptr, nullptr, nullptr, nullptr, nullptr, nullptr, nullptr, nullptr,  64,  64, W_rad, nullptr, nullptr, R, 128, 128);

    // scoring + top-128
    score_select_kernel<<<512, 256, 0, stream>>>(R, I, Ws1, bs1, Ws2, bs2, IDX);

    // LN stats
    stats_kernel<<<32768, 256, 0, stream>>>(R, MR, PTOK);
    kv_stats_kernel<<<16384, 256, 0, stream>>>(I, IDX, MRKV);

    // qh / khvh
    mgemm<AM_LN,  EP_NONE><<<dim3(1024, 1), 256, 0, stream>>>(R, nullptr, nullptr, nullptr, nullptr, MR, g_q, b_q, nullptr, 128, 0, Wqkv, nullptr, bqkv, QH, 128, 128);
    mgemm<AM_LNG, EP_NONE><<<dim3(512, 2), 256, 0, stream>>>(I, nullptr, nullptr, nullptr, IDX, MRKV, g_kv, b_kv, nullptr, 128, 0, Wqkv + 16384, nullptr, bqkv + 128, KVH, 256, 256);

    // attention in place; rad2 = R + ao@Wo^T + bo
    attn_kernel<<<4096, 256, 0, stream>>>(QH, KVH);
    mgemm<AM_TOK, EP_RES><<<dim3(1024, 1), 256, 0, stream>>>(QH, nullptr, nullptr, nullptr, nullptr, nullptr, nullptr, nullptr, nullptr, 128, 0, Wo, nullptr, bo, R, 128, 128);

    // FFN (LN folded), hidden chunked through d_out in 2 halves
    stats_kernel<<<32768, 256, 0, stream>>>(R, MR, PTOK);
    for (int hfl = 0; hfl < 2; ++hfl) {
        const size_t off = (size_t)hfl * 65536u;
        mgemm<AM_LN,  EP_RELU><<<dim3(512, 4), 256, 0, stream>>>(R + off * 128, nullptr, nullptr, nullptr, nullptr, MR + off * 2, g2, b2, nullptr, 128, 0, Wf1, nullptr, bf1, T1, 512, 512);
        mgemm<AM_TOK, EP_RES ><<<dim3(512, 1), 256, 0, stream>>>(T1, nullptr, nullptr, nullptr, nullptr, nullptr, nullptr, nullptr, nullptr, 512, 0, Wf2, nullptr, bf2, R + off * 128, 128, 128);
    }

    // xz: x -> U, z -> V
    mgemm<AM_CAT, EP_NONE><<<dim3(1024, 2), 256, 0, stream>>>(R, I, nullptr, nullptr, nullptr, nullptr, nullptr, nullptr, nullptr, 256, 0, W_hin, nullptr, nullptr, U, 256, 256);
    mgemm<AM_CAT, EP_NONE><<<dim3(1024, 2), 256, 0, stream>>>(R, I, nullptr, nullptr, nullptr, nullptr, nullptr, nullptr, nullptr, 256, 0, W_hin + 65536, nullptr, nullptr, V, 256, 256);

    // depthwise causal conv + silu, in place: U: x -> xs
    dwconv_kernel<<<512, 256, 0, stream>>>(U, conv_dw, b_dw);

    // SSM in 2 token-halves
    for (int hfl = 0; hfl < 2; ++hfl) {
        const size_t off = (size_t)hfl * 65536u;
        u16* xs = U + off * 256;
        u16* z  = V + off * 256;
        mgemm<AM_TOK, EP_SP  ><<<dim3(512, 2), 256, 0, stream>>>(xs, nullptr, nullptr, nullptr, nullptr, nullptr, nullptr, nullptr, nullptr, 256, 0, W_dt, nullptr, b_dt, DT, 256, 256);
        mgemm<AM_TOK, EP_NONE><<<dim3(512, 1), 256, 0, stream>>>(xs, nullptr, nullptr, nullptr, nullptr, nullptr, nullptr, nullptr, nullptr, 256, 0, W_Bp, W_Cp, nullptr, BC, 32, 32);
        scan_kernel<<<512, 256, 0, stream>>>(xs, DT, BC, A_log, YF, YB);
        mgemm<AM_FIN, EP_NONE><<<dim3(512, 1), 256, 0, stream>>>(YF, YB, xs, z, nullptr, nullptr, nullptr, nullptr, Dp, 256, 0, W_hout, nullptr, nullptr, HMB, 128, 128);
        precomb_kernel<<<32768, 256, 0, stream>>>(R + off * 128, HMB, gamma, gammah);
        mgemm<AM_TOK, EP_NONE><<<dim3(512, 1), 256, 0, stream>>>(HMB, nullptr, nullptr, nullptr, nullptr, nullptr, nullptr, nullptr, nullptr, 128, 0, W_delta, nullptr, nullptr, DC + off * 64, 64, 64);
    }

    // gate + radar_enh + fuse_in (U, xs dead)
    gate_kernel<<<512, 256, 0, stream>>>(radar, image, Wg, bg, DC, U);

    // final 3x3 conv (implicit MFMA GEMM) + BN + relu -> d_out fp32 NCHW
    conv3x3_mfma<<<dim3(1024, 2), 256, 0, stream>>>(U, Wc, bn_g, bn_b, bn_m, bn_v, out);
}